// Round 10
// baseline (755.161 us; speedup 1.0000x reference)
//
#include <hip/hip_runtime.h>
#include <math.h>

// ---------------------------------------------------------------------------
// GeometricAttentionLayer: B=2, N=2048, C=64, MV=16, D=64, H=8, BLADE=9
// R23: (a) revert R22's read-reorder (was -1.5%; compiler re-schedules
// anyway) -> R21 schedule everywhere. (b) gemm_split_8p converted from
// 16x16x32 to 32x32x16 MFMA: 48 instead of 96 MFMA/wave/tile at a 15%
// better rate (2382 vs 2075 TF ubench) — attacks the MFMA-issue floor that
// R20-R22 showed is the binding term. Fragment path (frag_off32 reads +
// C/D map) is the one gemm_bf16 has used verified since R13 on the SAME
// staged LDS format. Same staging, pacing 3/3/2/0, barrier-free inner
// tile, one __syncthreads per K-tile. PTILE = exact R21.
// ---------------------------------------------------------------------------

typedef __bf16 bf16x8 __attribute__((ext_vector_type(8)));
typedef __bf16 bf16x4 __attribute__((ext_vector_type(4)));
typedef float floatx4 __attribute__((ext_vector_type(4)));
typedef float floatx16 __attribute__((ext_vector_type(16)));

__constant__ int c_ip[8] = {0, 2, 3, 4, 8, 9, 10, 14};

// ---------------------------------------------------------------------------
// prep2: one block per output row (coalesced, LDS-staged weights).
// ---------------------------------------------------------------------------
__global__ __launch_bounds__(256) void prep2(
    const float* __restrict__ x, const float* __restrict__ blade,
    const float* __restrict__ w_q, const float* __restrict__ w_k,
    const float* __restrict__ w_v, const float* __restrict__ w_o,
    __bf16* __restrict__ xh, __bf16* __restrict__ xl,
    __bf16* __restrict__ wbqkh, __bf16* __restrict__ wbqkl,
    __bf16* __restrict__ wbv, __bf16* __restrict__ wbo)
{
  __shared__ float sw[4608];
  __shared__ float sbl[144];
  const int blk = blockIdx.x;
  const int tid = threadIdx.x;

  if (blk < 4608) {            // ---- wbqk row (hi/lo) ----
    int n = blk;
    const float* wrow;
    int y;
    if (n < 4096) {            // q rows: n = h*512 + d*8 + e ; j = d*8+h
      int e = n & 7, d = (n >> 3) & 63, h = n >> 9;
      wrow = w_q + (size_t)(d * 8 + h) * 576;
      y = c_ip[e];
    } else {                   // k rows: n-4096 = d*8 + e ; j = d
      int n2 = n - 4096;
      int e = n2 & 7, d = n2 >> 3;
      wrow = w_k + (size_t)d * 576;
      y = c_ip[e];
    }
    for (int t = tid; t < 576; t += 256) sw[t] = wrow[t];
    if (tid < 144) sbl[tid] = blade[(tid >> 4) * 256 + (tid & 15) * 16 + y];
    __syncthreads();
#pragma unroll
    for (int kq = 0; kq < 4; kq++) {
      int k = kq * 256 + tid;            // k = i*16 + x
      int i = k >> 4, xx = k & 15;
      float s = 0.f;
#pragma unroll
      for (int b = 0; b < 9; b++) s += sw[i * 9 + b] * sbl[b * 16 + xx];
      __bf16 h16 = (__bf16)s;
      wbqkh[(size_t)n * 1024 + k] = h16;
      wbqkl[(size_t)n * 1024 + k] = (__bf16)(s - (float)h16);
    }
  } else if (blk < 5632) {     // ---- wbv row ----
    int n = blk - 4608;        // n = d*16 + mv ; y = mv
    int d = n >> 4, y = n & 15;
    const float* wrow = w_v + (size_t)d * 576;
    for (int t = tid; t < 576; t += 256) sw[t] = wrow[t];
    if (tid < 144) sbl[tid] = blade[(tid >> 4) * 256 + (tid & 15) * 16 + y];
    __syncthreads();
#pragma unroll
    for (int kq = 0; kq < 4; kq++) {
      int k = kq * 256 + tid;
      int i = k >> 4, xx = k & 15;
      float s = 0.f;
#pragma unroll
      for (int b = 0; b < 9; b++) s += sw[i * 9 + b] * sbl[b * 16 + xx];
      wbv[(size_t)n * 1024 + k] = (__bf16)s;
    }
  } else if (blk < 6656) {     // ---- wbo row ----
    int n = blk - 5632;        // n = c*16 + y
    int c = n >> 4, y = n & 15;
    const float* wrow = w_o + (size_t)c * 4608;   // w_o[c, ich, b]
    for (int t = tid; t < 4608; t += 256) sw[t] = wrow[t];
    if (tid < 144) sbl[tid] = blade[(tid >> 4) * 256 + (tid & 15) * 16 + y];
    __syncthreads();
#pragma unroll
    for (int kq = 0; kq < 32; kq++) {
      int k = kq * 256 + tid;            // k = h*1024 + d*16 + mv
      int ich = (k >> 10) * 64 + ((k >> 4) & 63);
      int mv = k & 15;
      float s = 0.f;
#pragma unroll
      for (int b = 0; b < 9; b++) s += sw[ich * 9 + b] * sbl[b * 16 + mv];
      wbo[(size_t)n * 8192 + k] = (__bf16)s;
    }
  } else {                     // ---- x split (float4) ----
    int idx = (blk - 6656) * 256 + tid;  // over 4096*1024/4
    float4 v = ((const float4*)x)[idx];
    bf16x4 h, l;
    h.x = (__bf16)v.x; l.x = (__bf16)(v.x - (float)h.x);
    h.y = (__bf16)v.y; l.y = (__bf16)(v.y - (float)h.y);
    h.z = (__bf16)v.z; l.z = (__bf16)(v.z - (float)h.z);
    h.w = (__bf16)v.w; l.w = (__bf16)(v.w - (float)h.w);
    *(bf16x4*)(xh + (size_t)idx * 4) = h;
    *(bf16x4*)(xl + (size_t)idx * 4) = l;
  }
}

// sum 4 partial f32 buffers (each n elements) into out
__global__ __launch_bounds__(256) void reduce4(
    const float* __restrict__ p, float* __restrict__ out, int n)
{
  int i = (blockIdx.x * 256 + threadIdx.x) * 4;
  if (i >= n) return;
  float4 a = *(const float4*)(p + i);
  float4 b = *(const float4*)(p + (size_t)n + i);
  float4 c = *(const float4*)(p + 2 * (size_t)n + i);
  float4 d = *(const float4*)(p + 3 * (size_t)n + i);
  *(float4*)(out + i) = make_float4(a.x + b.x + c.x + d.x, a.y + b.y + c.y + d.y,
                                    a.z + b.z + c.z + d.z, a.w + b.w + c.w + d.w);
}

// ---------------------------------------------------------------------------
static __device__ __forceinline__ void gll16(const __bf16* g, __bf16* l) {
  __builtin_amdgcn_global_load_lds(
      (const __attribute__((address_space(1))) void*)g,
      (__attribute__((address_space(3))) void*)l, 16, 0, 0);
}

// GROUP-panel swizzle (L2 locality). TS = tile size in elements (square).
template <int GROUP, int TS>
static __device__ __forceinline__ void swizzle_mn(int& m0, int& n0) {
  int gn = gridDim.x;
  int flat = blockIdx.y * gn + blockIdx.x;
  int panel = flat / (GROUP * gn);
  int r = flat - panel * GROUP * gn;
  m0 = (panel * GROUP + (r % GROUP)) * TS;
  n0 = (r / GROUP) * TS;
}

// Rectangular-tile variant: TSM x TSN tiles (bijective for any grid).
template <int GROUP, int TSM, int TSN>
static __device__ __forceinline__ void swizzle_mn2(int& m0, int& n0) {
  int gn = gridDim.x;
  int flat = blockIdx.y * gn + blockIdx.x;
  int panel = flat / (GROUP * gn);
  int r = flat - panel * GROUP * gn;
  m0 = (panel * GROUP + (r % GROUP)) * TSM;
  n0 = (r / GROUP) * TSN;
}

// LDS slot of (row, logical k16-step t, k-half kh) under the staging swizzle.
static __device__ __forceinline__ int frag_off32(int row, int t, int kh) {
  return row * 32 + 8 * ((2 * t + kh) ^ ((row >> 1) & 3));
}

// ---------------------------------------------------------------------------
// Plain bf16 MFMA GEMM (32x32x16): C = alpha * A * Bt^T. 128x128, BK=32.
// EPI: 0 = f32 store, 3 = bf16 store. z-batched via element strides.
// ---------------------------------------------------------------------------
template <int EPI>
__global__ __launch_bounds__(256) void gemm_bf16(
    const __bf16* __restrict__ A, int lda, long long sAz,
    const __bf16* __restrict__ Bt, int ldb, long long sBz,
    void* __restrict__ C0v, int ldc, long long sCz,
    int K, float alpha)
{
  __shared__ __bf16 As[128 * 32];
  __shared__ __bf16 Bs[128 * 32];
  const int tid = threadIdx.x;
  const int wave = tid >> 6, lane = tid & 63;
  int m0, n0;
  swizzle_mn<4, 128>(m0, n0);
  A  += (size_t)blockIdx.z * sAz;
  Bt += (size_t)blockIdx.z * sBz;

  const int srow = lane >> 2;
  const int skk = 8 * ((lane & 3) ^ ((lane >> 3) & 3));
  const __bf16* gA0 = A  + (size_t)(m0 + wave * 32      + srow) * lda + skk;
  const __bf16* gA1 = A  + (size_t)(m0 + wave * 32 + 16 + srow) * lda + skk;
  const __bf16* gB0 = Bt + (size_t)(n0 + wave * 32      + srow) * ldb + skk;
  const __bf16* gB1 = Bt + (size_t)(n0 + wave * 32 + 16 + srow) * ldb + skk;
  const int ldsoff = wave * 1024;

  const int l31 = lane & 31, kh = lane >> 5;
  const int wm = (wave & 1) * 64, wn = (wave >> 1) * 64;
  int aoff[2][2], boff[2][2];
#pragma unroll
  for (int i = 0; i < 2; i++)
#pragma unroll
    for (int t = 0; t < 2; t++) {
      aoff[i][t] = frag_off32(wm + i * 32 + l31, t, kh);
      boff[i][t] = frag_off32(wn + i * 32 + l31, t, kh);
    }

  floatx16 acc[2][2];
#pragma unroll
  for (int i = 0; i < 2; i++)
#pragma unroll
    for (int j = 0; j < 2; j++)
#pragma unroll
      for (int e = 0; e < 16; e++) acc[i][j][e] = 0.f;

  for (int k0 = 0; k0 < K; k0 += 32) {
    gll16(gA0, As + ldsoff); gll16(gA1, As + ldsoff + 512);
    gll16(gB0, Bs + ldsoff); gll16(gB1, Bs + ldsoff + 512);
    gA0 += 32; gA1 += 32; gB0 += 32; gB1 += 32;
    __syncthreads();
    bf16x8 af[2][2], bfv[2][2];
#pragma unroll
    for (int i = 0; i < 2; i++)
#pragma unroll
      for (int t = 0; t < 2; t++) {
        af[i][t]  = *(const bf16x8*)(As + aoff[i][t]);
        bfv[i][t] = *(const bf16x8*)(Bs + boff[i][t]);
      }
#pragma unroll
    for (int t = 0; t < 2; t++)
#pragma unroll
      for (int i = 0; i < 2; i++)
#pragma unroll
        for (int j = 0; j < 2; j++)
          acc[i][j] = __builtin_amdgcn_mfma_f32_32x32x16_bf16(
              af[i][t], bfv[j][t], acc[i][j], 0, 0, 0);
    __syncthreads();
  }

  // C/D: col = lane&31, row = (reg&3) + 8*(reg>>2) + 4*kh  [m74/m101]
  const int rb = m0 + wm + 4 * kh;
  const int cb = n0 + wn + l31;
#pragma unroll
  for (int i = 0; i < 2; i++) {
#pragma unroll
    for (int j = 0; j < 2; j++) {
      int c = cb + j * 32;
#pragma unroll
      for (int q = 0; q < 4; q++) {
        int r = rb + i * 32 + 8 * q;
        float v0 = acc[i][j][q * 4 + 0] * alpha;
        float v1 = acc[i][j][q * 4 + 1] * alpha;
        float v2 = acc[i][j][q * 4 + 2] * alpha;
        float v3 = acc[i][j][q * 4 + 3] * alpha;
        if (EPI == 0) {
          float* C = (float*)C0v + (size_t)blockIdx.z * sCz;
          float* p = C + (size_t)r * ldc + c;
          p[0] = v0; p[ldc] = v1; p[2 * ldc] = v2; p[3 * ldc] = v3;
        } else {  // EPI == 3: bf16 store
          __bf16* C = (__bf16*)C0v + (size_t)blockIdx.z * sCz;
          C[(size_t)r * ldc + c] = (__bf16)v0;
          C[(size_t)(r + 1) * ldc + c] = (__bf16)v1;
          C[(size_t)(r + 2) * ldc + c] = (__bf16)v2;
          C[(size_t)(r + 3) * ldc + c] = (__bf16)v3;
        }
      }
    }
  }
}

// ---------------------------------------------------------------------------
// Fused split-bf16 GEMM (16x16x32, conflict-free):
// C = alpha * (Ah*Bh^T + Al*Bh^T + Ah*Bl^T). 48 MFMA per 32-k step.
// EPI: 0 = f32 store, 2 = split hi/lo bf16 store. GROUP=8 swizzle.
// ---------------------------------------------------------------------------
template <int EPI>
__global__ __launch_bounds__(256) void gemm_split(
    const __bf16* __restrict__ Ah, const __bf16* __restrict__ Al, int lda, long long sAz,
    const __bf16* __restrict__ Bh, const __bf16* __restrict__ Bl, int ldb, long long sBz,
    void* __restrict__ C0v, void* __restrict__ C1v, int ldc, long long sCz,
    int K, float alpha)
{
  __shared__ __bf16 Ash[128 * 32];
  __shared__ __bf16 Asl[128 * 32];
  __shared__ __bf16 Bsh[128 * 32];
  __shared__ __bf16 Bsl[128 * 32];
  const int tid = threadIdx.x;
  const int wave = tid >> 6, lane = tid & 63;
  int m0, n0;
  swizzle_mn<8, 128>(m0, n0);
  Ah += (size_t)blockIdx.z * sAz;
  Al += (size_t)blockIdx.z * sAz;
  Bh += (size_t)blockIdx.z * sBz;
  Bl += (size_t)blockIdx.z * sBz;

  const int srow = lane >> 2;
  const int skk = 8 * ((lane & 3) ^ ((lane >> 3) & 3));
  const size_t ao0 = (size_t)(m0 + wave * 32      + srow) * lda + skk;
  const size_t ao1 = (size_t)(m0 + wave * 32 + 16 + srow) * lda + skk;
  const size_t bo0 = (size_t)(n0 + wave * 32      + srow) * ldb + skk;
  const size_t bo1 = (size_t)(n0 + wave * 32 + 16 + srow) * ldb + skk;
  const __bf16 *gAh0 = Ah + ao0, *gAh1 = Ah + ao1;
  const __bf16 *gAl0 = Al + ao0, *gAl1 = Al + ao1;
  const __bf16 *gBh0 = Bh + bo0, *gBh1 = Bh + bo1;
  const __bf16 *gBl0 = Bl + bo0, *gBl1 = Bl + bo1;
  const int ldsoff = wave * 1024;

  const int fr = lane & 15, fq = lane >> 4;
  const int wm = (wave & 1) * 64, wn = (wave >> 1) * 64;
  int aoff[4], boff[4];
#pragma unroll
  for (int t = 0; t < 4; t++) {
    int rA = wm + t * 16 + fr;
    aoff[t] = rA * 32 + 8 * (fq ^ ((rA >> 1) & 3));
    int rB = wn + t * 16 + fr;
    boff[t] = rB * 32 + 8 * (fq ^ ((rB >> 1) & 3));
  }

  floatx4 acc[4][4];
#pragma unroll
  for (int i = 0; i < 4; i++)
#pragma unroll
    for (int j = 0; j < 4; j++) acc[i][j] = (floatx4){0.f, 0.f, 0.f, 0.f};

  for (int k0 = 0; k0 < K; k0 += 32) {
    gll16(gAh0, Ash + ldsoff); gll16(gAh1, Ash + ldsoff + 512);
    gll16(gAl0, Asl + ldsoff); gll16(gAl1, Asl + ldsoff + 512);
    gll16(gBh0, Bsh + ldsoff); gll16(gBh1, Bsh + ldsoff + 512);
    gll16(gBl0, Bsl + ldsoff); gll16(gBl1, Bsl + ldsoff + 512);
    gAh0 += 32; gAh1 += 32; gAl0 += 32; gAl1 += 32;
    gBh0 += 32; gBh1 += 32; gBl0 += 32; gBl1 += 32;
    __syncthreads();
    bf16x8 afh[4], afl[4], bfh[4], bfl[4];
#pragma unroll
    for (int t = 0; t < 4; t++) {
      afh[t] = *(const bf16x8*)(Ash + aoff[t]);
      afl[t] = *(const bf16x8*)(Asl + aoff[t]);
      bfh[t] = *(const bf16x8*)(Bsh + boff[t]);
      bfl[t] = *(const bf16x8*)(Bsl + boff[t]);
    }
#pragma unroll
    for (int i = 0; i < 4; i++)
#pragma unroll
      for (int j = 0; j < 4; j++) {
        acc[i][j] = __builtin_amdgcn_mfma_f32_16x16x32_bf16(
            afh[i], bfh[j], acc[i][j], 0, 0, 0);
        acc[i][j] = __builtin_amdgcn_mfma_f32_16x16x32_bf16(
            afl[i], bfh[j], acc[i][j], 0, 0, 0);
        acc[i][j] = __builtin_amdgcn_mfma_f32_16x16x32_bf16(
            afh[i], bfl[j], acc[i][j], 0, 0, 0);
      }
    __syncthreads();
  }

  const int rb = m0 + wm + fq * 4;
  const int cb = n0 + wn + fr;
#pragma unroll
  for (int i = 0; i < 4; i++) {
#pragma unroll
    for (int j = 0; j < 4; j++) {
      float vv[4] = {acc[i][j].x * alpha, acc[i][j].y * alpha,
                     acc[i][j].z * alpha, acc[i][j].w * alpha};
      int r = rb + i * 16, c = cb + j * 16;
      if (EPI == 0) {
        float* C = (float*)C0v + (size_t)blockIdx.z * sCz;
        float* p = C + (size_t)r * ldc + c;
        p[0] = vv[0]; p[ldc] = vv[1]; p[2 * ldc] = vv[2]; p[3 * ldc] = vv[3];
      } else {  // EPI == 2: split hi/lo
        __bf16* Hp = (__bf16*)C0v + (size_t)blockIdx.z * sCz;
        __bf16* Lp = (__bf16*)C1v + (size_t)blockIdx.z * sCz;
#pragma unroll
        for (int t = 0; t < 4; t++) {
          size_t o = (size_t)(r + t) * ldc + c;
          __bf16 hh = (__bf16)vv[t];
          Hp[o] = hh;
          Lp[o] = (__bf16)(vv[t] - (float)hh);
        }
      }
    }
  }
}

// ---------------------------------------------------------------------------
// R23: 8-phase 256x256 split-bf16 GEMM on 32x32x16 MFMA. 8 waves, BK=32,
// 8 statically distinct LDS buffers. Per wave: 4 m-frags x 2 n-frags of
// 32x32, acc = floatx16[4][2]; per K-tile 4 phases of 12 MFMA (one m-frag
// each: {hh,lh,hl} x 2 n-frags x 2 k-halfsteps). Barrier-free inner tile,
// loads 3/3/2/0, one __syncthreads per K-tile. Fragment reads + C/D map
// identical to the verified gemm_bf16 path (same staged LDS format).
// EPI: 0 = f32 store (alpha), 2 = split hi/lo bf16 store.
// ---------------------------------------------------------------------------
#define MFMA32(a, b, c) c = __builtin_amdgcn_mfma_f32_32x32x16_bf16(a, b, c, 0, 0, 0)

#define MFMA_FRAG32(I)                                                      \
  __builtin_amdgcn_s_setprio(1);                                            \
  MFMA32(ah0, bh00, acc[I][0]); MFMA32(ah0, bh10, acc[I][1]);               \
  MFMA32(al0, bh00, acc[I][0]); MFMA32(al0, bh10, acc[I][1]);               \
  MFMA32(ah0, bl00, acc[I][0]); MFMA32(ah0, bl10, acc[I][1]);               \
  MFMA32(ah1, bh01, acc[I][0]); MFMA32(ah1, bh11, acc[I][1]);               \
  MFMA32(al1, bh01, acc[I][0]); MFMA32(al1, bh11, acc[I][1]);               \
  MFMA32(ah1, bl01, acc[I][0]); MFMA32(ah1, bl11, acc[I][1]);               \
  __builtin_amdgcn_s_setprio(0)

#define TILE8P(SAh, SAl, SBh, SBl, DAh, DAl, DBh, DBl, PF)                  \
  do {                                                                      \
    bf16x8 bh00 = *(const bf16x8*)(SBh + boff[0][0]);                       \
    bf16x8 bh01 = *(const bf16x8*)(SBh + boff[0][1]);                       \
    bf16x8 bh10 = *(const bf16x8*)(SBh + boff[1][0]);                       \
    bf16x8 bh11 = *(const bf16x8*)(SBh + boff[1][1]);                       \
    bf16x8 bl00 = *(const bf16x8*)(SBl + boff[0][0]);                       \
    bf16x8 bl01 = *(const bf16x8*)(SBl + boff[0][1]);                       \
    bf16x8 bl10 = *(const bf16x8*)(SBl + boff[1][0]);                       \
    bf16x8 bl11 = *(const bf16x8*)(SBl + boff[1][1]);                       \
    { /* ---- phase 0: m-frag 0 ; 3 gll ---- */                             \
      bf16x8 ah0 = *(const bf16x8*)(SAh + aoff[0][0]);                      \
      bf16x8 ah1 = *(const bf16x8*)(SAh + aoff[0][1]);                      \
      bf16x8 al0 = *(const bf16x8*)(SAl + aoff[0][0]);                      \
      bf16x8 al1 = *(const bf16x8*)(SAl + aoff[0][1]);                      \
      if (PF) { gll16(pAh0, DAh + lw); gll16(pAh1, DAh + lw + 512);         \
                gll16(pAl0, DAl + lw);                                      \
                pAh0 += 32; pAh1 += 32; pAl0 += 32; }                       \
      MFMA_FRAG32(0);                                                       \
    }                                                                       \
    { /* ---- phase 1: m-frag 1 ; 3 gll ---- */                             \
      bf16x8 ah0 = *(const bf16x8*)(SAh + aoff[1][0]);                      \
      bf16x8 ah1 = *(const bf16x8*)(SAh + aoff[1][1]);                      \
      bf16x8 al0 = *(const bf16x8*)(SAl + aoff[1][0]);                      \
      bf16x8 al1 = *(const bf16x8*)(SAl + aoff[1][1]);                      \
      if (PF) { gll16(pAl1, DAl + lw + 512);                                \
                gll16(pBh0, DBh + lw); gll16(pBh1, DBh + lw + 512);         \
                pAl1 += 32; pBh0 += 32; pBh1 += 32; }                       \
      MFMA_FRAG32(1);                                                       \
    }                                                                       \
    { /* ---- phase 2: m-frag 2 ; 2 gll ---- */                             \
      bf16x8 ah0 = *(const bf16x8*)(SAh + aoff[2][0]);                      \
      bf16x8 ah1 = *(const bf16x8*)(SAh + aoff[2][1]);                      \
      bf16x8 al0 = *(const bf16x8*)(SAl + aoff[2][0]);                      \
      bf16x8 al1 = *(const bf16x8*)(SAl + aoff[2][1]);                      \
      if (PF) { gll16(pBl0, DBl + lw); gll16(pBl1, DBl + lw + 512);         \
                pBl0 += 32; pBl1 += 32; }                                   \
      MFMA_FRAG32(2);                                                       \
    }                                                                       \
    { /* ---- phase 3: m-frag 3 ; NO loads ; boundary drain ---- */         \
      bf16x8 ah0 = *(const bf16x8*)(SAh + aoff[3][0]);                      \
      bf16x8 ah1 = *(const bf16x8*)(SAh + aoff[3][1]);                      \
      bf16x8 al0 = *(const bf16x8*)(SAl + aoff[3][0]);                      \
      bf16x8 al1 = *(const bf16x8*)(SAl + aoff[3][1]);                      \
      MFMA_FRAG32(3);                                                       \
    }                                                                       \
    __syncthreads();                                                        \
  } while (0)

template <int EPI>
__global__ __launch_bounds__(512) void gemm_split_8p(
    const __bf16* __restrict__ Ah, const __bf16* __restrict__ Al, int lda, long long sAz,
    const __bf16* __restrict__ Bh, const __bf16* __restrict__ Bl, int ldb, long long sBz,
    void* __restrict__ C0v, void* __restrict__ C1v, int ldc, long long sCz,
    int K, float alpha)
{
  // 8 statically distinct buffers: [4 matrices] x [double buffer], 16 KB each
  __shared__ __bf16 sAh0[256 * 32], sAl0[256 * 32], sBh0[256 * 32], sBl0[256 * 32];
  __shared__ __bf16 sAh1[256 * 32], sAl1[256 * 32], sBh1[256 * 32], sBl1[256 * 32];
  const int tid = threadIdx.x;
  const int wave = tid >> 6, lane = tid & 63;
  int m0, n0;
  swizzle_mn<4, 256>(m0, n0);
  Ah += (size_t)blockIdx.z * sAz;
  Al += (size_t)blockIdx.z * sAz;
  Bh += (size_t)blockIdx.z * sBz;
  Bl += (size_t)blockIdx.z * sBz;

  // staging: wave w loads rows [w*32, w*32+32) of each matrix k-slab,
  // pre-swizzled on the global side (same involution as the fragment reads)
  const int srow = lane >> 2;
  const int skk = 8 * ((lane & 3) ^ ((lane >> 3) & 3));
  const __bf16* pAh0 = Ah + (size_t)(m0 + wave * 32 + srow) * lda + skk;
  const __bf16* pAh1 = pAh0 + (size_t)16 * lda;
  const __bf16* pAl0 = Al + (size_t)(m0 + wave * 32 + srow) * lda + skk;
  const __bf16* pAl1 = pAl0 + (size_t)16 * lda;
  const __bf16* pBh0 = Bh + (size_t)(n0 + wave * 32 + srow) * ldb + skk;
  const __bf16* pBh1 = pBh0 + (size_t)16 * ldb;
  const __bf16* pBl0 = Bl + (size_t)(n0 + wave * 32 + srow) * ldb + skk;
  const __bf16* pBl1 = pBl0 + (size_t)16 * ldb;
  const int lw = wave * 1024;   // 32 rows * 32 elems per wave

  // fragment geometry (32x32): wave tile 128(m) x 64(n);
  // 4 m-frags of 32 rows, 2 n-frags of 32 cols; 2 k-halfsteps per BK=32.
  const int l31 = lane & 31, kh = lane >> 5;
  const int wm = (wave >> 2) * 128, wn = (wave & 3) * 64;
  int aoff[4][2], boff[2][2];
#pragma unroll
  for (int i = 0; i < 4; i++)
#pragma unroll
    for (int t = 0; t < 2; t++)
      aoff[i][t] = frag_off32(wm + i * 32 + l31, t, kh);
#pragma unroll
  for (int j = 0; j < 2; j++)
#pragma unroll
    for (int t = 0; t < 2; t++)
      boff[j][t] = frag_off32(wn + j * 32 + l31, t, kh);

  floatx16 acc[4][2];
#pragma unroll
  for (int i = 0; i < 4; i++)
#pragma unroll
    for (int j = 0; j < 2; j++)
#pragma unroll
      for (int e = 0; e < 16; e++) acc[i][j][e] = 0.f;

  const int ktiles = K >> 5;          // must be even

  // prologue: stage tile 0 into set 0
  gll16(pAh0, sAh0 + lw); gll16(pAh1, sAh0 + lw + 512); pAh0 += 32; pAh1 += 32;
  gll16(pAl0, sAl0 + lw); gll16(pAl1, sAl0 + lw + 512); pAl0 += 32; pAl1 += 32;
  gll16(pBh0, sBh0 + lw); gll16(pBh1, sBh0 + lw + 512); pBh0 += 32; pBh1 += 32;
  gll16(pBl0, sBl0 + lw); gll16(pBl1, sBl0 + lw + 512); pBl0 += 32; pBl1 += 32;
  __syncthreads();

  for (int it = 0; it < (ktiles >> 1); ++it) {
    TILE8P(sAh0, sAl0, sBh0, sBl0, sAh1, sAl1, sBh1, sBl1,
           (2 * it + 1 < ktiles));
    TILE8P(sAh1, sAl1, sBh1, sBl1, sAh0, sAl0, sBh0, sBl0,
           (2 * it + 2 < ktiles));
  }

  // epilogue: C/D map col = lane&31, row = (reg&3) + 8*(reg>>2) + 4*kh
  const int rb = m0 + wm + 4 * kh;
  const int cb = n0 + wn + l31;
#pragma unroll
  for (int i = 0; i < 4; i++) {
#pragma unroll
    for (int j = 0; j < 2; j++) {
      int c = cb + j * 32;
#pragma unroll
      for (int q = 0; q < 4; q++) {
        int r = rb + i * 32 + 8 * q;
        float v0 = acc[i][j][q * 4 + 0] * alpha;
        float v1 = acc[i][j][q * 4 + 1] * alpha;
        float v2 = acc[i][j][q * 4 + 2] * alpha;
        float v3 = acc[i][j][q * 4 + 3] * alpha;
        if (EPI == 0) {
          float* C = (float*)C0v + (size_t)blockIdx.z * sCz;
          float* p = C + (size_t)r * ldc + c;
          p[0] = v0; p[ldc] = v1; p[2 * ldc] = v2; p[3 * ldc] = v3;
        } else {  // EPI == 2: split hi/lo bf16
          __bf16* Hp = (__bf16*)C0v + (size_t)blockIdx.z * sCz;
          __bf16* Lp = (__bf16*)C1v + (size_t)blockIdx.z * sCz;
          float vv[4] = {v0, v1, v2, v3};
#pragma unroll
          for (int s = 0; s < 4; s++) {
            size_t o = (size_t)(r + s) * ldc + c;
            __bf16 hh = (__bf16)vv[s];
            Hp[o] = hh;
            Lp[o] = (__bf16)(vv[s] - (float)hh);
          }
        }
      }
    }
  }
}

// ---------------------------------------------------------------------------
// 8-phase plain-bf16 GEMM, tile 256(m) x 128(n), BK=64 as two 32-k slabs.
// R21 schedule: NO mid-tile barriers; loads 2/2/2/0; 4 phases of 8 MFMA.
// 8 waves as 4Mx2N (64x64/wave), acc[4][4]; 96 KB LDS; one __syncthreads
// per K-tile. EPI: 0 = f32 store, 3 = bf16 store.
// ---------------------------------------------------------------------------
#define MFMA1(a, b, c) c = __builtin_amdgcn_mfma_f32_16x16x32_bf16(a, b, c, 0, 0, 0)

#define PTILE(SA0, SA1, SB0, SB1, DA0, DA1, DB0, DB1, PF)                   \
  do {                                                                      \
    /* ---- phase 0: b0 frags + i=0,1 khalf0 ; 2 A loads ---- */            \
    bf16x8 b0[4], b1[4];                                                    \
    _Pragma("unroll") for (int j = 0; j < 4; j++)                           \
      b0[j] = *(const bf16x8*)(SB0 + boff[j]);                              \
    bf16x8 a00 = *(const bf16x8*)(SA0 + aoff[0]);                           \
    bf16x8 a10 = *(const bf16x8*)(SA0 + aoff[1]);                           \
    if (PF) { gll16(pA0, DA0 + lw); gll16(pA1, DA0 + lw + 512); }           \
    __builtin_amdgcn_s_setprio(1);                                          \
    _Pragma("unroll") for (int j = 0; j < 4; j++) {                         \
      MFMA1(a00, b0[j], acc[0][j]); MFMA1(a10, b0[j], acc[1][j]);           \
    }                                                                       \
    __builtin_amdgcn_s_setprio(0);                                          \
    /* ---- phase 1: b1 frags + i=0,1 khalf1 ; 2 A loads ---- */            \
    _Pragma("unroll") for (int j = 0; j < 4; j++)                           \
      b1[j] = *(const bf16x8*)(SB1 + boff[j]);                              \
    bf16x8 a01 = *(const bf16x8*)(SA1 + aoff[0]);                           \
    bf16x8 a11 = *(const bf16x8*)(SA1 + aoff[1]);                           \
    if (PF) { gll16(pA0 + 32, DA1 + lw); gll16(pA1 + 32, DA1 + lw + 512);   \
              pA0 += 64; pA1 += 64; }                                       \
    __builtin_amdgcn_s_setprio(1);                                          \
    _Pragma("unroll") for (int j = 0; j < 4; j++) {                         \
      MFMA1(a01, b1[j], acc[0][j]); MFMA1(a11, b1[j], acc[1][j]);           \
    }                                                                       \
    __builtin_amdgcn_s_setprio(0);                                          \
    /* ---- phase 2: i=2,3 khalf0 ; 2 B loads ---- */                       \
    bf16x8 a20 = *(const bf16x8*)(SA0 + aoff[2]);                           \
    bf16x8 a30 = *(const bf16x8*)(SA0 + aoff[3]);                           \
    if (PF) { gll16(pB0, DB0 + lwB); gll16(pB0 + 32, DB1 + lwB);            \
              pB0 += 64; }                                                  \
    __builtin_amdgcn_s_setprio(1);                                          \
    _Pragma("unroll") for (int j = 0; j < 4; j++) {                         \
      MFMA1(a20, b0[j], acc[2][j]); MFMA1(a30, b0[j], acc[3][j]);           \
    }                                                                       \
    __builtin_amdgcn_s_setprio(0);                                          \
    /* ---- phase 3: i=2,3 khalf1 ; NO loads ; boundary drain ---- */       \
    bf16x8 a21 = *(const bf16x8*)(SA1 + aoff[2]);                           \
    bf16x8 a31 = *(const bf16x8*)(SA1 + aoff[3]);                           \
    __builtin_amdgcn_s_setprio(1);                                          \
    _Pragma("unroll") for (int j = 0; j < 4; j++) {                         \
      MFMA1(a21, b1[j], acc[2][j]); MFMA1(a31, b1[j], acc[3][j]);           \
    }                                                                       \
    __builtin_amdgcn_s_setprio(0);                                          \
    __syncthreads();                                                        \
  } while (0)

template <int EPI>
__global__ __launch_bounds__(512) void gemm_bf16_8p(
    const __bf16* __restrict__ A, int lda, long long sAz,
    const __bf16* __restrict__ Bt, int ldb, long long sBz,
    void* __restrict__ C0v, int ldc, long long sCz,
    int K, float alpha)
{
  // A slabs 256x32 (16 KB), B slabs 128x32 (8 KB); x2 k-halves x2 dbuf = 96 KB
  __shared__ __bf16 sA0_0[256 * 32], sA1_0[256 * 32];
  __shared__ __bf16 sB0_0[128 * 32], sB1_0[128 * 32];
  __shared__ __bf16 sA0_1[256 * 32], sA1_1[256 * 32];
  __shared__ __bf16 sB0_1[128 * 32], sB1_1[128 * 32];
  const int tid = threadIdx.x;
  const int wave = tid >> 6, lane = tid & 63;
  int m0, n0;
  swizzle_mn2<4, 256, 128>(m0, n0);
  A  += (size_t)blockIdx.z * sAz;
  Bt += (size_t)blockIdx.z * sBz;

  // staging (global-side XOR pre-swizzle, same involution as frag reads):
  // A: wave stages rows [w*32, w*32+32); B: rows [w*16, w*16+16).
  const int srow = lane >> 2;
  const int skk = 8 * ((lane & 3) ^ ((lane >> 3) & 3));
  const __bf16* pA0 = A + (size_t)(m0 + wave * 32 + srow) * lda + skk;
  const __bf16* pA1 = pA0 + (size_t)16 * lda;
  const __bf16* pB0 = Bt + (size_t)(n0 + wave * 16 + srow) * ldb + skk;
  const int lw = wave * 1024;   // A: 32 rows * 32 elems
  const int lwB = wave * 512;   // B: 16 rows * 32 elems

  // fragment geometry: wave tile 64(m) x 64(n); 4 m-frags, 4 n-frags
  const int fr = lane & 15, fq = lane >> 4;
  const int wm = (wave >> 1) * 64, wn = (wave & 1) * 64;
  int aoff[4], boff[4];
#pragma unroll
  for (int i = 0; i < 4; i++) {
    int rA = wm + i * 16 + fr;
    aoff[i] = rA * 32 + 8 * (fq ^ ((rA >> 1) & 3));
    int rB = wn + i * 16 + fr;
    boff[i] = rB * 32 + 8 * (fq ^ ((rB >> 1) & 3));
  }

  floatx4 acc[4][4];
#pragma unroll
  for (int i = 0; i < 4; i++)
#pragma unroll
    for (int j = 0; j < 4; j++) acc[i][j] = (floatx4){0.f, 0.f, 0.f, 0.f};

  const int ktiles = K >> 6;          // BK=64; must be even

  // prologue: stage tile 0 into set 0
  gll16(pA0, sA0_0 + lw); gll16(pA1, sA0_0 + lw + 512);
  gll16(pA0 + 32, sA1_0 + lw); gll16(pA1 + 32, sA1_0 + lw + 512);
  gll16(pB0, sB0_0 + lwB); gll16(pB0 + 32, sB1_0 + lwB);
  pA0 += 64; pA1 += 64; pB0 += 64;
  __syncthreads();

  for (int it = 0; it < (ktiles >> 1); ++it) {
    PTILE(sA0_0, sA1_0, sB0_0, sB1_0, sA0_1, sA1_1, sB0_1, sB1_1,
          (2 * it + 1 < ktiles));
    PTILE(sA0_1, sA1_1, sB0_1, sB1_1, sA0_0, sA1_0, sB0_0, sB1_0,
          (2 * it + 2 < ktiles));
  }

  // epilogue: C/D map col=lane&15, row=(lane>>4)*4+reg
  const int rb = m0 + wm + fq * 4;
  const int cb = n0 + wn + fr;
#pragma unroll
  for (int i = 0; i < 4; i++) {
#pragma unroll
    for (int j = 0; j < 4; j++) {
      int r = rb + i * 16, c = cb + j * 16;
      float vv[4] = {acc[i][j].x * alpha, acc[i][j].y * alpha,
                     acc[i][j].z * alpha, acc[i][j].w * alpha};
      if (EPI == 0) {
        float* C = (float*)C0v + (size_t)blockIdx.z * sCz;
        float* p = C + (size_t)r * ldc + c;
        p[0] = vv[0]; p[ldc] = vv[1]; p[2 * ldc] = vv[2]; p[3 * ldc] = vv[3];
      } else {  // EPI == 3: bf16 store
        __bf16* C = (__bf16*)C0v + (size_t)blockIdx.z * sCz;
        C[(size_t)r * ldc + c] = (__bf16)vv[0];
        C[(size_t)(r + 1) * ldc + c] = (__bf16)vv[1];
        C[(size_t)(r + 2) * ldc + c] = (__bf16)vv[2];
        C[(size_t)(r + 3) * ldc + c] = (__bf16)vv[3];
      }
    }
  }
}

// ---------------------------------------------------------------------------
// Wave-per-row in-place softmax: f32 row [2048] -> bf16 into same row.
// ---------------------------------------------------------------------------
__global__ __launch_bounds__(256) void softmax_wave(float* __restrict__ Pf)
{
  const int wave = threadIdx.x >> 6, lane = threadIdx.x & 63;
  const size_t row = (size_t)blockIdx.x * 4 + wave;
  float* p = Pf + row * 2048;
  __bf16* q = (__bf16*)p;

  float4 v[8];
  float m = -1e30f;
#pragma unroll
  for (int t = 0; t < 8; t++) {
    v[t] = ((const float4*)p)[lane + t * 64];
    m = fmaxf(m, fmaxf(fmaxf(v[t].x, v[t].y), fmaxf(v[t].z, v[t].w)));
  }
#pragma unroll
  for (int off = 32; off; off >>= 1) m = fmaxf(m, __shfl_xor(m, off, 64));

  float s = 0.f;
#pragma unroll
  for (int t = 0; t < 8; t++) {
    v[t].x = expf(v[t].x - m); v[t].y = expf(v[t].y - m);
    v[t].z = expf(v[t].z - m); v[t].w = expf(v[t].w - m);
    s += (v[t].x + v[t].y) + (v[t].z + v[t].w);
  }
#pragma unroll
  for (int off = 32; off; off >>= 1) s += __shfl_xor(s, off, 64);
  float inv = 1.0f / s;

#pragma unroll
  for (int t = 0; t < 8; t++) {
    bf16x4 o;
    o.x = (__bf16)(v[t].x * inv); o.y = (__bf16)(v[t].y * inv);
    o.z = (__bf16)(v[t].z * inv); o.w = (__bf16)(v[t].w * inv);
    *(bf16x4*)(q + (lane + t * 64) * 4) = o;
  }
}

// ---------------------------------------------------------------------------
extern "C" void kernel_launch(void* const* d_in, const int* in_sizes, int n_in,
                              void* d_out, int out_size, void* d_ws, size_t ws_size,
                              hipStream_t stream)
{
  (void)in_sizes; (void)n_in; (void)out_size; (void)ws_size;
  const float* x     = (const float*)d_in[0];
  const float* blade = (const float*)d_in[1];
  const float* w_q   = (const float*)d_in[2];
  const float* w_k   = (const float*)d_in[3];
  const float* w_v   = (const float*)d_in[4];
  const float* w_o   = (const float*)d_in[5];
  float* out = (float*)d_out;

  // --- fixed aliased workspace plan (peak 234,881,024 B; ws >= 256 MB) -----
  char* base = (char*)d_ws;
  __bf16* wbo   = (__bf16*)(base);                  //  16.78 MB [1024,8192]
  __bf16* vT    = (__bf16*)(base + 16777216);       //   8.39 MB [1024,4096]
  __bf16* qkmh  = (__bf16*)(base + 25165824);       //  37.75 MB [4096,4608]
  __bf16* qkml  = (__bf16*)(base + 62914560);       //  37.75 MB
  char* scr = base + 100663296;
  // phase 1 (aliases Pf region):
  __bf16* xh    = (__bf16*)(scr);                   //   8.39 MB [4096,1024]
  __bf16* xl    = (__bf16*)(scr + 8388608);         //   8.39 MB
  __bf16* wbqkh = (__bf16*)(scr + 16777216);        //   9.44 MB [4608,1024]
  __bf16* wbqkl = (__bf16*)(scr + 26214400);        //   9.44 MB
  __bf16* wbv   = (__bf16*)(scr + 35651584);        //   2.10 MB [1024,1024]
  // phase 2/3:
  float*  Pf    = (float*)(scr);                    //  67.11 MB [4,2048,2048]
  __bf16* A2    = (__bf16*)(scr + 67108864);        //  33.55 MB [2048,8192]
  float*  Part  = (float*)(scr + 100663296);        //  33.55 MB [4,2048,1024]

  dim3 blk(256);
  const float scale = 0.04419417382415922f;  // 1/sqrt(512)

  // --- phase 1: prep + projections ----------------------------------------
  prep2<<<10752, blk, 0, stream>>>(x, blade, w_q, w_k, w_v, w_o,
                                   xh, xl, wbqkh, wbqkl, wbv, wbo);

  // qkm q-part: [4096,1024] x [4096,1024]^T -> cols 0..4095 of qkm.
  // 256^2 8-phase (32x32 MFMA): grid 16x16 = 256 blocks = 1 per CU.
  gemm_split_8p<2><<<dim3(16, 16, 1), dim3(512), 0, stream>>>(
      xh, xl, 1024, 0, wbqkh, wbqkl, 1024, 0,
      qkmh, qkml, 4608, 0, 1024, 1.f);

  // qkm km-part: [4096,1024] x [512,1024]^T -> cols 4096..4607 of qkm.
  gemm_split<2><<<dim3(4, 32, 1), blk, 0, stream>>>(
      xh, xl, 1024, 0,
      wbqkh + (size_t)4096 * 1024, wbqkl + (size_t)4096 * 1024, 1024, 0,
      qkmh + 4096, qkml + 4096, 4608, 0, 1024, 1.f);

  // vT = wbv * xh^T : [1024,1024] x [4096,1024]^T -> [1024,4096] bf16
  gemm_bf16<3><<<dim3(32, 8, 1), blk, 0, stream>>>(
      wbv, 1024, 0, xh, 1024, 0, vT, 4096, 0, 1024, 1.f);

  // --- phase 2/3: attention + O-projection per batch -----------------------
  for (int b = 0; b < 2; b++) {
    const __bf16* qh_b  = qkmh + (size_t)b * 2048 * 4608;
    const __bf16* ql_b  = qkml + (size_t)b * 2048 * 4608;
    const __bf16* kmh_b = qh_b + 4096;   // km cols 4096..4607, ldb 4608
    const __bf16* kml_b = ql_b + 4096;

    for (int h0 = 0; h0 < 8; h0 += 4) {
      // scores -> Pf [z,2048,2048] f32 (z = head in group)
      // 8-phase 256^2 tiles (32x32 MFMA): grid 8x8x4 = 256 blocks = 1/CU
      gemm_split_8p<0><<<dim3(8, 8, 4), dim3(512), 0, stream>>>(
          qh_b + h0 * 512, ql_b + h0 * 512, 4608, 512,
          kmh_b, kml_b, 4608, 0,
          Pf, nullptr, 2048, (long long)2048 * 2048, 512, scale);
      // softmax in place: bf16 P into Pf rows (row stride 4096 bf16 units)
      softmax_wave<<<4 * 2048 / 4, blk, 0, stream>>>(Pf);
      // PV: P [z,2048,2048] * vT_b^T -> A2 cols (h0+z)*1024
      // 8-phase 256x128 tiles: grid 8x8x4 = 256 blocks = 1 per CU
      gemm_bf16_8p<3><<<dim3(8, 8, 4), dim3(512), 0, stream>>>(
          (const __bf16*)Pf, 4096, (long long)2048 * 4096,
          vT + (size_t)b * 2048, 4096, 0,
          A2 + (size_t)h0 * 1024, 8192, 1024, 2048, 1.f);
    }

    // O-proj: A2 [2048,8192] x wbo [1024,8192]^T, split-K=4 -> partials
    // 8-phase 256x128 tiles: grid 8x8x4 = 256 blocks = 1 per CU
    gemm_bf16_8p<0><<<dim3(8, 8, 4), dim3(512), 0, stream>>>(
        A2, 8192, 2048, wbo, 8192, 2048,
        Part, 1024, (long long)2048 * 1024, 2048, 1.f);
    reduce4<<<2048, blk, 0, stream>>>(Part, out + (size_t)b * 2048 * 1024,
                                      2048 * 1024);
  }
}

// Round 11
// 736.395 us; speedup vs baseline: 1.0255x; 1.0255x over previous
//
#include <hip/hip_runtime.h>
#include <math.h>

// ---------------------------------------------------------------------------
// GeometricAttentionLayer: B=2, N=2048, C=64, MV=16, D=64, H=8, BLADE=9
// R24: fix R23's 32x32 bank conflicts (6.29M/dispatch). Root cause: 32x32
// A/B-frag reads have lanes 0-31 on 32 DISTINCT rows at the SAME k-slot;
// the old swizzle key ((r>>1)&3) has period 8 -> lanes {0,8,16,24} hit the
// same 4 banks (4-way). Fix: period-32 key ((r>>1)&3)^((r>>3)&3), applied
// BOTH sides (rule #21): staging skk gains ^((lane>>5)&1), the +16-row
// stage pointer uses skk^16 (key XOR 2), reads use frag_off32b. Only
// gemm_split_8p touched; everything else identical to R23 (= R21).
// ---------------------------------------------------------------------------

typedef __bf16 bf16x8 __attribute__((ext_vector_type(8)));
typedef __bf16 bf16x4 __attribute__((ext_vector_type(4)));
typedef float floatx4 __attribute__((ext_vector_type(4)));
typedef float floatx16 __attribute__((ext_vector_type(16)));

__constant__ int c_ip[8] = {0, 2, 3, 4, 8, 9, 10, 14};

// ---------------------------------------------------------------------------
// prep2: one block per output row (coalesced, LDS-staged weights).
// ---------------------------------------------------------------------------
__global__ __launch_bounds__(256) void prep2(
    const float* __restrict__ x, const float* __restrict__ blade,
    const float* __restrict__ w_q, const float* __restrict__ w_k,
    const float* __restrict__ w_v, const float* __restrict__ w_o,
    __bf16* __restrict__ xh, __bf16* __restrict__ xl,
    __bf16* __restrict__ wbqkh, __bf16* __restrict__ wbqkl,
    __bf16* __restrict__ wbv, __bf16* __restrict__ wbo)
{
  __shared__ float sw[4608];
  __shared__ float sbl[144];
  const int blk = blockIdx.x;
  const int tid = threadIdx.x;

  if (blk < 4608) {            // ---- wbqk row (hi/lo) ----
    int n = blk;
    const float* wrow;
    int y;
    if (n < 4096) {            // q rows: n = h*512 + d*8 + e ; j = d*8+h
      int e = n & 7, d = (n >> 3) & 63, h = n >> 9;
      wrow = w_q + (size_t)(d * 8 + h) * 576;
      y = c_ip[e];
    } else {                   // k rows: n-4096 = d*8 + e ; j = d
      int n2 = n - 4096;
      int e = n2 & 7, d = n2 >> 3;
      wrow = w_k + (size_t)d * 576;
      y = c_ip[e];
    }
    for (int t = tid; t < 576; t += 256) sw[t] = wrow[t];
    if (tid < 144) sbl[tid] = blade[(tid >> 4) * 256 + (tid & 15) * 16 + y];
    __syncthreads();
#pragma unroll
    for (int kq = 0; kq < 4; kq++) {
      int k = kq * 256 + tid;            // k = i*16 + x
      int i = k >> 4, xx = k & 15;
      float s = 0.f;
#pragma unroll
      for (int b = 0; b < 9; b++) s += sw[i * 9 + b] * sbl[b * 16 + xx];
      __bf16 h16 = (__bf16)s;
      wbqkh[(size_t)n * 1024 + k] = h16;
      wbqkl[(size_t)n * 1024 + k] = (__bf16)(s - (float)h16);
    }
  } else if (blk < 5632) {     // ---- wbv row ----
    int n = blk - 4608;        // n = d*16 + mv ; y = mv
    int d = n >> 4, y = n & 15;
    const float* wrow = w_v + (size_t)d * 576;
    for (int t = tid; t < 576; t += 256) sw[t] = wrow[t];
    if (tid < 144) sbl[tid] = blade[(tid >> 4) * 256 + (tid & 15) * 16 + y];
    __syncthreads();
#pragma unroll
    for (int kq = 0; kq < 4; kq++) {
      int k = kq * 256 + tid;
      int i = k >> 4, xx = k & 15;
      float s = 0.f;
#pragma unroll
      for (int b = 0; b < 9; b++) s += sw[i * 9 + b] * sbl[b * 16 + xx];
      wbv[(size_t)n * 1024 + k] = (__bf16)s;
    }
  } else if (blk < 6656) {     // ---- wbo row ----
    int n = blk - 5632;        // n = c*16 + y
    int c = n >> 4, y = n & 15;
    const float* wrow = w_o + (size_t)c * 4608;   // w_o[c, ich, b]
    for (int t = tid; t < 4608; t += 256) sw[t] = wrow[t];
    if (tid < 144) sbl[tid] = blade[(tid >> 4) * 256 + (tid & 15) * 16 + y];
    __syncthreads();
#pragma unroll
    for (int kq = 0; kq < 32; kq++) {
      int k = kq * 256 + tid;            // k = h*1024 + d*16 + mv
      int ich = (k >> 10) * 64 + ((k >> 4) & 63);
      int mv = k & 15;
      float s = 0.f;
#pragma unroll
      for (int b = 0; b < 9; b++) s += sw[ich * 9 + b] * sbl[b * 16 + mv];
      wbo[(size_t)n * 8192 + k] = (__bf16)s;
    }
  } else {                     // ---- x split (float4) ----
    int idx = (blk - 6656) * 256 + tid;  // over 4096*1024/4
    float4 v = ((const float4*)x)[idx];
    bf16x4 h, l;
    h.x = (__bf16)v.x; l.x = (__bf16)(v.x - (float)h.x);
    h.y = (__bf16)v.y; l.y = (__bf16)(v.y - (float)h.y);
    h.z = (__bf16)v.z; l.z = (__bf16)(v.z - (float)h.z);
    h.w = (__bf16)v.w; l.w = (__bf16)(v.w - (float)h.w);
    *(bf16x4*)(xh + (size_t)idx * 4) = h;
    *(bf16x4*)(xl + (size_t)idx * 4) = l;
  }
}

// sum 4 partial f32 buffers (each n elements) into out
__global__ __launch_bounds__(256) void reduce4(
    const float* __restrict__ p, float* __restrict__ out, int n)
{
  int i = (blockIdx.x * 256 + threadIdx.x) * 4;
  if (i >= n) return;
  float4 a = *(const float4*)(p + i);
  float4 b = *(const float4*)(p + (size_t)n + i);
  float4 c = *(const float4*)(p + 2 * (size_t)n + i);
  float4 d = *(const float4*)(p + 3 * (size_t)n + i);
  *(float4*)(out + i) = make_float4(a.x + b.x + c.x + d.x, a.y + b.y + c.y + d.y,
                                    a.z + b.z + c.z + d.z, a.w + b.w + c.w + d.w);
}

// ---------------------------------------------------------------------------
static __device__ __forceinline__ void gll16(const __bf16* g, __bf16* l) {
  __builtin_amdgcn_global_load_lds(
      (const __attribute__((address_space(1))) void*)g,
      (__attribute__((address_space(3))) void*)l, 16, 0, 0);
}

// GROUP-panel swizzle (L2 locality). TS = tile size in elements (square).
template <int GROUP, int TS>
static __device__ __forceinline__ void swizzle_mn(int& m0, int& n0) {
  int gn = gridDim.x;
  int flat = blockIdx.y * gn + blockIdx.x;
  int panel = flat / (GROUP * gn);
  int r = flat - panel * GROUP * gn;
  m0 = (panel * GROUP + (r % GROUP)) * TS;
  n0 = (r / GROUP) * TS;
}

// Rectangular-tile variant: TSM x TSN tiles (bijective for any grid).
template <int GROUP, int TSM, int TSN>
static __device__ __forceinline__ void swizzle_mn2(int& m0, int& n0) {
  int gn = gridDim.x;
  int flat = blockIdx.y * gn + blockIdx.x;
  int panel = flat / (GROUP * gn);
  int r = flat - panel * GROUP * gn;
  m0 = (panel * GROUP + (r % GROUP)) * TSM;
  n0 = (r / GROUP) * TSN;
}

// LDS slot of (row, logical k16-step t, k-half kh), period-8 key (16x16 path).
static __device__ __forceinline__ int frag_off32(int row, int t, int kh) {
  return row * 32 + 8 * ((2 * t + kh) ^ ((row >> 1) & 3));
}

// Period-32 key variant for 32-row fragment reads (R24): avoids the 4-way
// bank conflict among rows {r, r+8, r+16, r+24}.
static __device__ __forceinline__ int frag_off32b(int row, int t, int kh) {
  return row * 32 + 8 * ((2 * t + kh) ^ ((row >> 1) & 3) ^ ((row >> 3) & 3));
}

// ---------------------------------------------------------------------------
// Plain bf16 MFMA GEMM (32x32x16): C = alpha * A * Bt^T. 128x128, BK=32.
// EPI: 0 = f32 store, 3 = bf16 store. z-batched via element strides.
// ---------------------------------------------------------------------------
template <int EPI>
__global__ __launch_bounds__(256) void gemm_bf16(
    const __bf16* __restrict__ A, int lda, long long sAz,
    const __bf16* __restrict__ Bt, int ldb, long long sBz,
    void* __restrict__ C0v, int ldc, long long sCz,
    int K, float alpha)
{
  __shared__ __bf16 As[128 * 32];
  __shared__ __bf16 Bs[128 * 32];
  const int tid = threadIdx.x;
  const int wave = tid >> 6, lane = tid & 63;
  int m0, n0;
  swizzle_mn<4, 128>(m0, n0);
  A  += (size_t)blockIdx.z * sAz;
  Bt += (size_t)blockIdx.z * sBz;

  const int srow = lane >> 2;
  const int skk = 8 * ((lane & 3) ^ ((lane >> 3) & 3));
  const __bf16* gA0 = A  + (size_t)(m0 + wave * 32      + srow) * lda + skk;
  const __bf16* gA1 = A  + (size_t)(m0 + wave * 32 + 16 + srow) * lda + skk;
  const __bf16* gB0 = Bt + (size_t)(n0 + wave * 32      + srow) * ldb + skk;
  const __bf16* gB1 = Bt + (size_t)(n0 + wave * 32 + 16 + srow) * ldb + skk;
  const int ldsoff = wave * 1024;

  const int l31 = lane & 31, kh = lane >> 5;
  const int wm = (wave & 1) * 64, wn = (wave >> 1) * 64;
  int aoff[2][2], boff[2][2];
#pragma unroll
  for (int i = 0; i < 2; i++)
#pragma unroll
    for (int t = 0; t < 2; t++) {
      aoff[i][t] = frag_off32(wm + i * 32 + l31, t, kh);
      boff[i][t] = frag_off32(wn + i * 32 + l31, t, kh);
    }

  floatx16 acc[2][2];
#pragma unroll
  for (int i = 0; i < 2; i++)
#pragma unroll
    for (int j = 0; j < 2; j++)
#pragma unroll
      for (int e = 0; e < 16; e++) acc[i][j][e] = 0.f;

  for (int k0 = 0; k0 < K; k0 += 32) {
    gll16(gA0, As + ldsoff); gll16(gA1, As + ldsoff + 512);
    gll16(gB0, Bs + ldsoff); gll16(gB1, Bs + ldsoff + 512);
    gA0 += 32; gA1 += 32; gB0 += 32; gB1 += 32;
    __syncthreads();
    bf16x8 af[2][2], bfv[2][2];
#pragma unroll
    for (int i = 0; i < 2; i++)
#pragma unroll
      for (int t = 0; t < 2; t++) {
        af[i][t]  = *(const bf16x8*)(As + aoff[i][t]);
        bfv[i][t] = *(const bf16x8*)(Bs + boff[i][t]);
      }
#pragma unroll
    for (int t = 0; t < 2; t++)
#pragma unroll
      for (int i = 0; i < 2; i++)
#pragma unroll
        for (int j = 0; j < 2; j++)
          acc[i][j] = __builtin_amdgcn_mfma_f32_32x32x16_bf16(
              af[i][t], bfv[j][t], acc[i][j], 0, 0, 0);
    __syncthreads();
  }

  // C/D: col = lane&31, row = (reg&3) + 8*(reg>>2) + 4*kh  [m74/m101]
  const int rb = m0 + wm + 4 * kh;
  const int cb = n0 + wn + l31;
#pragma unroll
  for (int i = 0; i < 2; i++) {
#pragma unroll
    for (int j = 0; j < 2; j++) {
      int c = cb + j * 32;
#pragma unroll
      for (int q = 0; q < 4; q++) {
        int r = rb + i * 32 + 8 * q;
        float v0 = acc[i][j][q * 4 + 0] * alpha;
        float v1 = acc[i][j][q * 4 + 1] * alpha;
        float v2 = acc[i][j][q * 4 + 2] * alpha;
        float v3 = acc[i][j][q * 4 + 3] * alpha;
        if (EPI == 0) {
          float* C = (float*)C0v + (size_t)blockIdx.z * sCz;
          float* p = C + (size_t)r * ldc + c;
          p[0] = v0; p[ldc] = v1; p[2 * ldc] = v2; p[3 * ldc] = v3;
        } else {  // EPI == 3: bf16 store
          __bf16* C = (__bf16*)C0v + (size_t)blockIdx.z * sCz;
          C[(size_t)r * ldc + c] = (__bf16)v0;
          C[(size_t)(r + 1) * ldc + c] = (__bf16)v1;
          C[(size_t)(r + 2) * ldc + c] = (__bf16)v2;
          C[(size_t)(r + 3) * ldc + c] = (__bf16)v3;
        }
      }
    }
  }
}

// ---------------------------------------------------------------------------
// Fused split-bf16 GEMM (16x16x32, conflict-free):
// C = alpha * (Ah*Bh^T + Al*Bh^T + Ah*Bl^T). 48 MFMA per 32-k step.
// EPI: 0 = f32 store, 2 = split hi/lo bf16 store. GROUP=8 swizzle.
// ---------------------------------------------------------------------------
template <int EPI>
__global__ __launch_bounds__(256) void gemm_split(
    const __bf16* __restrict__ Ah, const __bf16* __restrict__ Al, int lda, long long sAz,
    const __bf16* __restrict__ Bh, const __bf16* __restrict__ Bl, int ldb, long long sBz,
    void* __restrict__ C0v, void* __restrict__ C1v, int ldc, long long sCz,
    int K, float alpha)
{
  __shared__ __bf16 Ash[128 * 32];
  __shared__ __bf16 Asl[128 * 32];
  __shared__ __bf16 Bsh[128 * 32];
  __shared__ __bf16 Bsl[128 * 32];
  const int tid = threadIdx.x;
  const int wave = tid >> 6, lane = tid & 63;
  int m0, n0;
  swizzle_mn<8, 128>(m0, n0);
  Ah += (size_t)blockIdx.z * sAz;
  Al += (size_t)blockIdx.z * sAz;
  Bh += (size_t)blockIdx.z * sBz;
  Bl += (size_t)blockIdx.z * sBz;

  const int srow = lane >> 2;
  const int skk = 8 * ((lane & 3) ^ ((lane >> 3) & 3));
  const size_t ao0 = (size_t)(m0 + wave * 32      + srow) * lda + skk;
  const size_t ao1 = (size_t)(m0 + wave * 32 + 16 + srow) * lda + skk;
  const size_t bo0 = (size_t)(n0 + wave * 32      + srow) * ldb + skk;
  const size_t bo1 = (size_t)(n0 + wave * 32 + 16 + srow) * ldb + skk;
  const __bf16 *gAh0 = Ah + ao0, *gAh1 = Ah + ao1;
  const __bf16 *gAl0 = Al + ao0, *gAl1 = Al + ao1;
  const __bf16 *gBh0 = Bh + bo0, *gBh1 = Bh + bo1;
  const __bf16 *gBl0 = Bl + bo0, *gBl1 = Bl + bo1;
  const int ldsoff = wave * 1024;

  const int fr = lane & 15, fq = lane >> 4;
  const int wm = (wave & 1) * 64, wn = (wave >> 1) * 64;
  int aoff[4], boff[4];
#pragma unroll
  for (int t = 0; t < 4; t++) {
    int rA = wm + t * 16 + fr;
    aoff[t] = rA * 32 + 8 * (fq ^ ((rA >> 1) & 3));
    int rB = wn + t * 16 + fr;
    boff[t] = rB * 32 + 8 * (fq ^ ((rB >> 1) & 3));
  }

  floatx4 acc[4][4];
#pragma unroll
  for (int i = 0; i < 4; i++)
#pragma unroll
    for (int j = 0; j < 4; j++) acc[i][j] = (floatx4){0.f, 0.f, 0.f, 0.f};

  for (int k0 = 0; k0 < K; k0 += 32) {
    gll16(gAh0, Ash + ldsoff); gll16(gAh1, Ash + ldsoff + 512);
    gll16(gAl0, Asl + ldsoff); gll16(gAl1, Asl + ldsoff + 512);
    gll16(gBh0, Bsh + ldsoff); gll16(gBh1, Bsh + ldsoff + 512);
    gll16(gBl0, Bsl + ldsoff); gll16(gBl1, Bsl + ldsoff + 512);
    gAh0 += 32; gAh1 += 32; gAl0 += 32; gAl1 += 32;
    gBh0 += 32; gBh1 += 32; gBl0 += 32; gBl1 += 32;
    __syncthreads();
    bf16x8 afh[4], afl[4], bfh[4], bfl[4];
#pragma unroll
    for (int t = 0; t < 4; t++) {
      afh[t] = *(const bf16x8*)(Ash + aoff[t]);
      afl[t] = *(const bf16x8*)(Asl + aoff[t]);
      bfh[t] = *(const bf16x8*)(Bsh + boff[t]);
      bfl[t] = *(const bf16x8*)(Bsl + boff[t]);
    }
#pragma unroll
    for (int i = 0; i < 4; i++)
#pragma unroll
      for (int j = 0; j < 4; j++) {
        acc[i][j] = __builtin_amdgcn_mfma_f32_16x16x32_bf16(
            afh[i], bfh[j], acc[i][j], 0, 0, 0);
        acc[i][j] = __builtin_amdgcn_mfma_f32_16x16x32_bf16(
            afl[i], bfh[j], acc[i][j], 0, 0, 0);
        acc[i][j] = __builtin_amdgcn_mfma_f32_16x16x32_bf16(
            afh[i], bfl[j], acc[i][j], 0, 0, 0);
      }
    __syncthreads();
  }

  const int rb = m0 + wm + fq * 4;
  const int cb = n0 + wn + fr;
#pragma unroll
  for (int i = 0; i < 4; i++) {
#pragma unroll
    for (int j = 0; j < 4; j++) {
      float vv[4] = {acc[i][j].x * alpha, acc[i][j].y * alpha,
                     acc[i][j].z * alpha, acc[i][j].w * alpha};
      int r = rb + i * 16, c = cb + j * 16;
      if (EPI == 0) {
        float* C = (float*)C0v + (size_t)blockIdx.z * sCz;
        float* p = C + (size_t)r * ldc + c;
        p[0] = vv[0]; p[ldc] = vv[1]; p[2 * ldc] = vv[2]; p[3 * ldc] = vv[3];
      } else {  // EPI == 2: split hi/lo
        __bf16* Hp = (__bf16*)C0v + (size_t)blockIdx.z * sCz;
        __bf16* Lp = (__bf16*)C1v + (size_t)blockIdx.z * sCz;
#pragma unroll
        for (int t = 0; t < 4; t++) {
          size_t o = (size_t)(r + t) * ldc + c;
          __bf16 hh = (__bf16)vv[t];
          Hp[o] = hh;
          Lp[o] = (__bf16)(vv[t] - (float)hh);
        }
      }
    }
  }
}

// ---------------------------------------------------------------------------
// R24: 8-phase 256x256 split-bf16 GEMM on 32x32x16 MFMA with the period-32
// conflict-free swizzle (frag_off32b both sides). 8 waves, BK=32, 8
// statically distinct LDS buffers. Per wave: 4 m-frags x 2 n-frags of
// 32x32, acc = floatx16[4][2]; 4 phases of 12 MFMA; barrier-free inner
// tile; loads 3/3/2/0; one __syncthreads per K-tile.
// EPI: 0 = f32 store (alpha), 2 = split hi/lo bf16 store.
// ---------------------------------------------------------------------------
#define MFMA32(a, b, c) c = __builtin_amdgcn_mfma_f32_32x32x16_bf16(a, b, c, 0, 0, 0)

#define MFMA_FRAG32(I)                                                      \
  __builtin_amdgcn_s_setprio(1);                                            \
  MFMA32(ah0, bh00, acc[I][0]); MFMA32(ah0, bh10, acc[I][1]);               \
  MFMA32(al0, bh00, acc[I][0]); MFMA32(al0, bh10, acc[I][1]);               \
  MFMA32(ah0, bl00, acc[I][0]); MFMA32(ah0, bl10, acc[I][1]);               \
  MFMA32(ah1, bh01, acc[I][0]); MFMA32(ah1, bh11, acc[I][1]);               \
  MFMA32(al1, bh01, acc[I][0]); MFMA32(al1, bh11, acc[I][1]);               \
  MFMA32(ah1, bl01, acc[I][0]); MFMA32(ah1, bl11, acc[I][1]);               \
  __builtin_amdgcn_s_setprio(0)

#define TILE8P(SAh, SAl, SBh, SBl, DAh, DAl, DBh, DBl, PF)                  \
  do {                                                                      \
    bf16x8 bh00 = *(const bf16x8*)(SBh + boff[0][0]);                       \
    bf16x8 bh01 = *(const bf16x8*)(SBh + boff[0][1]);                       \
    bf16x8 bh10 = *(const bf16x8*)(SBh + boff[1][0]);                       \
    bf16x8 bh11 = *(const bf16x8*)(SBh + boff[1][1]);                       \
    bf16x8 bl00 = *(const bf16x8*)(SBl + boff[0][0]);                       \
    bf16x8 bl01 = *(const bf16x8*)(SBl + boff[0][1]);                       \
    bf16x8 bl10 = *(const bf16x8*)(SBl + boff[1][0]);                       \
    bf16x8 bl11 = *(const bf16x8*)(SBl + boff[1][1]);                       \
    { /* ---- phase 0: m-frag 0 ; 3 gll ---- */                             \
      bf16x8 ah0 = *(const bf16x8*)(SAh + aoff[0][0]);                      \
      bf16x8 ah1 = *(const bf16x8*)(SAh + aoff[0][1]);                      \
      bf16x8 al0 = *(const bf16x8*)(SAl + aoff[0][0]);                      \
      bf16x8 al1 = *(const bf16x8*)(SAl + aoff[0][1]);                      \
      if (PF) { gll16(pAh0, DAh + lw); gll16(pAh1, DAh + lw + 512);         \
                gll16(pAl0, DAl + lw);                                      \
                pAh0 += 32; pAh1 += 32; pAl0 += 32; }                       \
      MFMA_FRAG32(0);                                                       \
    }                                                                       \
    { /* ---- phase 1: m-frag 1 ; 3 gll ---- */                             \
      bf16x8 ah0 = *(const bf16x8*)(SAh + aoff[1][0]);                      \
      bf16x8 ah1 = *(const bf16x8*)(SAh + aoff[1][1]);                      \
      bf16x8 al0 = *(const bf16x8*)(SAl + aoff[1][0]);                      \
      bf16x8 al1 = *(const bf16x8*)(SAl + aoff[1][1]);                      \
      if (PF) { gll16(pAl1, DAl + lw + 512);                                \
                gll16(pBh0, DBh + lw); gll16(pBh1, DBh + lw + 512);         \
                pAl1 += 32; pBh0 += 32; pBh1 += 32; }                       \
      MFMA_FRAG32(1);                                                       \
    }                                                                       \
    { /* ---- phase 2: m-frag 2 ; 2 gll ---- */                             \
      bf16x8 ah0 = *(const bf16x8*)(SAh + aoff[2][0]);                      \
      bf16x8 ah1 = *(const bf16x8*)(SAh + aoff[2][1]);                      \
      bf16x8 al0 = *(const bf16x8*)(SAl + aoff[2][0]);                      \
      bf16x8 al1 = *(const bf16x8*)(SAl + aoff[2][1]);                      \
      if (PF) { gll16(pBl0, DBl + lw); gll16(pBl1, DBl + lw + 512);         \
                pBl0 += 32; pBl1 += 32; }                                   \
      MFMA_FRAG32(2);                                                       \
    }                                                                       \
    { /* ---- phase 3: m-frag 3 ; NO loads ; boundary drain ---- */         \
      bf16x8 ah0 = *(const bf16x8*)(SAh + aoff[3][0]);                      \
      bf16x8 ah1 = *(const bf16x8*)(SAh + aoff[3][1]);                      \
      bf16x8 al0 = *(const bf16x8*)(SAl + aoff[3][0]);                      \
      bf16x8 al1 = *(const bf16x8*)(SAl + aoff[3][1]);                      \
      MFMA_FRAG32(3);                                                       \
    }                                                                       \
    __syncthreads();                                                        \
  } while (0)

template <int EPI>
__global__ __launch_bounds__(512) void gemm_split_8p(
    const __bf16* __restrict__ Ah, const __bf16* __restrict__ Al, int lda, long long sAz,
    const __bf16* __restrict__ Bh, const __bf16* __restrict__ Bl, int ldb, long long sBz,
    void* __restrict__ C0v, void* __restrict__ C1v, int ldc, long long sCz,
    int K, float alpha)
{
  // 8 statically distinct buffers: [4 matrices] x [double buffer], 16 KB each
  __shared__ __bf16 sAh0[256 * 32], sAl0[256 * 32], sBh0[256 * 32], sBl0[256 * 32];
  __shared__ __bf16 sAh1[256 * 32], sAl1[256 * 32], sBh1[256 * 32], sBl1[256 * 32];
  const int tid = threadIdx.x;
  const int wave = tid >> 6, lane = tid & 63;
  int m0, n0;
  swizzle_mn<4, 256>(m0, n0);
  Ah += (size_t)blockIdx.z * sAz;
  Al += (size_t)blockIdx.z * sAz;
  Bh += (size_t)blockIdx.z * sBz;
  Bl += (size_t)blockIdx.z * sBz;

  // staging with period-32 key: rows 0-15 use skk (includes (lane>>5)&1 term
  // = (srow>>3)&1); rows 16-31 use skk^16 (key XOR 2). Global-side
  // pre-swizzle matches frag_off32b's read key exactly (both-sides rule).
  const int srow = lane >> 2;
  const int skk = 8 * ((lane & 3) ^ ((lane >> 3) & 3) ^ ((lane >> 5) & 1));
  const int skk2 = skk ^ 16;
  const __bf16* pAh0 = Ah + (size_t)(m0 + wave * 32 + srow) * lda + skk;
  const __bf16* pAh1 = Ah + (size_t)(m0 + wave * 32 + 16 + srow) * lda + skk2;
  const __bf16* pAl0 = Al + (size_t)(m0 + wave * 32 + srow) * lda + skk;
  const __bf16* pAl1 = Al + (size_t)(m0 + wave * 32 + 16 + srow) * lda + skk2;
  const __bf16* pBh0 = Bh + (size_t)(n0 + wave * 32 + srow) * ldb + skk;
  const __bf16* pBh1 = Bh + (size_t)(n0 + wave * 32 + 16 + srow) * ldb + skk2;
  const __bf16* pBl0 = Bl + (size_t)(n0 + wave * 32 + srow) * ldb + skk;
  const __bf16* pBl1 = Bl + (size_t)(n0 + wave * 32 + 16 + srow) * ldb + skk2;
  const int lw = wave * 1024;   // 32 rows * 32 elems per wave

  // fragment geometry (32x32): wave tile 128(m) x 64(n);
  // 4 m-frags of 32 rows, 2 n-frags of 32 cols; 2 k-halfsteps per BK=32.
  const int l31 = lane & 31, kh = lane >> 5;
  const int wm = (wave >> 2) * 128, wn = (wave & 3) * 64;
  int aoff[4][2], boff[2][2];
#pragma unroll
  for (int i = 0; i < 4; i++)
#pragma unroll
    for (int t = 0; t < 2; t++)
      aoff[i][t] = frag_off32b(wm + i * 32 + l31, t, kh);
#pragma unroll
  for (int j = 0; j < 2; j++)
#pragma unroll
    for (int t = 0; t < 2; t++)
      boff[j][t] = frag_off32b(wn + j * 32 + l31, t, kh);

  floatx16 acc[4][2];
#pragma unroll
  for (int i = 0; i < 4; i++)
#pragma unroll
    for (int j = 0; j < 2; j++)
#pragma unroll
      for (int e = 0; e < 16; e++) acc[i][j][e] = 0.f;

  const int ktiles = K >> 5;          // must be even

  // prologue: stage tile 0 into set 0
  gll16(pAh0, sAh0 + lw); gll16(pAh1, sAh0 + lw + 512); pAh0 += 32; pAh1 += 32;
  gll16(pAl0, sAl0 + lw); gll16(pAl1, sAl0 + lw + 512); pAl0 += 32; pAl1 += 32;
  gll16(pBh0, sBh0 + lw); gll16(pBh1, sBh0 + lw + 512); pBh0 += 32; pBh1 += 32;
  gll16(pBl0, sBl0 + lw); gll16(pBl1, sBl0 + lw + 512); pBl0 += 32; pBl1 += 32;
  __syncthreads();

  for (int it = 0; it < (ktiles >> 1); ++it) {
    TILE8P(sAh0, sAl0, sBh0, sBl0, sAh1, sAl1, sBh1, sBl1,
           (2 * it + 1 < ktiles));
    TILE8P(sAh1, sAl1, sBh1, sBl1, sAh0, sAl0, sBh0, sBl0,
           (2 * it + 2 < ktiles));
  }

  // epilogue: C/D map col = lane&31, row = (reg&3) + 8*(reg>>2) + 4*kh
  const int rb = m0 + wm + 4 * kh;
  const int cb = n0 + wn + l31;
#pragma unroll
  for (int i = 0; i < 4; i++) {
#pragma unroll
    for (int j = 0; j < 2; j++) {
      int c = cb + j * 32;
#pragma unroll
      for (int q = 0; q < 4; q++) {
        int r = rb + i * 32 + 8 * q;
        float v0 = acc[i][j][q * 4 + 0] * alpha;
        float v1 = acc[i][j][q * 4 + 1] * alpha;
        float v2 = acc[i][j][q * 4 + 2] * alpha;
        float v3 = acc[i][j][q * 4 + 3] * alpha;
        if (EPI == 0) {
          float* C = (float*)C0v + (size_t)blockIdx.z * sCz;
          float* p = C + (size_t)r * ldc + c;
          p[0] = v0; p[ldc] = v1; p[2 * ldc] = v2; p[3 * ldc] = v3;
        } else {  // EPI == 2: split hi/lo bf16
          __bf16* Hp = (__bf16*)C0v + (size_t)blockIdx.z * sCz;
          __bf16* Lp = (__bf16*)C1v + (size_t)blockIdx.z * sCz;
          float vv[4] = {v0, v1, v2, v3};
#pragma unroll
          for (int s = 0; s < 4; s++) {
            size_t o = (size_t)(r + s) * ldc + c;
            __bf16 hh = (__bf16)vv[s];
            Hp[o] = hh;
            Lp[o] = (__bf16)(vv[s] - (float)hh);
          }
        }
      }
    }
  }
}

// ---------------------------------------------------------------------------
// 8-phase plain-bf16 GEMM, tile 256(m) x 128(n), BK=64 as two 32-k slabs.
// R21 schedule: NO mid-tile barriers; loads 2/2/2/0; 4 phases of 8 MFMA.
// 8 waves as 4Mx2N (64x64/wave), acc[4][4]; 96 KB LDS; one __syncthreads
// per K-tile. EPI: 0 = f32 store, 3 = bf16 store.
// ---------------------------------------------------------------------------
#define MFMA1(a, b, c) c = __builtin_amdgcn_mfma_f32_16x16x32_bf16(a, b, c, 0, 0, 0)

#define PTILE(SA0, SA1, SB0, SB1, DA0, DA1, DB0, DB1, PF)                   \
  do {                                                                      \
    /* ---- phase 0: b0 frags + i=0,1 khalf0 ; 2 A loads ---- */            \
    bf16x8 b0[4], b1[4];                                                    \
    _Pragma("unroll") for (int j = 0; j < 4; j++)                           \
      b0[j] = *(const bf16x8*)(SB0 + boff[j]);                              \
    bf16x8 a00 = *(const bf16x8*)(SA0 + aoff[0]);                           \
    bf16x8 a10 = *(const bf16x8*)(SA0 + aoff[1]);                           \
    if (PF) { gll16(pA0, DA0 + lw); gll16(pA1, DA0 + lw + 512); }           \
    __builtin_amdgcn_s_setprio(1);                                          \
    _Pragma("unroll") for (int j = 0; j < 4; j++) {                         \
      MFMA1(a00, b0[j], acc[0][j]); MFMA1(a10, b0[j], acc[1][j]);           \
    }                                                                       \
    __builtin_amdgcn_s_setprio(0);                                          \
    /* ---- phase 1: b1 frags + i=0,1 khalf1 ; 2 A loads ---- */            \
    _Pragma("unroll") for (int j = 0; j < 4; j++)                           \
      b1[j] = *(const bf16x8*)(SB1 + boff[j]);                              \
    bf16x8 a01 = *(const bf16x8*)(SA1 + aoff[0]);                           \
    bf16x8 a11 = *(const bf16x8*)(SA1 + aoff[1]);                           \
    if (PF) { gll16(pA0 + 32, DA1 + lw); gll16(pA1 + 32, DA1 + lw + 512);   \
              pA0 += 64; pA1 += 64; }                                       \
    __builtin_amdgcn_s_setprio(1);                                          \
    _Pragma("unroll") for (int j = 0; j < 4; j++) {                         \
      MFMA1(a01, b1[j], acc[0][j]); MFMA1(a11, b1[j], acc[1][j]);           \
    }                                                                       \
    __builtin_amdgcn_s_setprio(0);                                          \
    /* ---- phase 2: i=2,3 khalf0 ; 2 B loads ---- */                       \
    bf16x8 a20 = *(const bf16x8*)(SA0 + aoff[2]);                           \
    bf16x8 a30 = *(const bf16x8*)(SA0 + aoff[3]);                           \
    if (PF) { gll16(pB0, DB0 + lwB); gll16(pB0 + 32, DB1 + lwB);            \
              pB0 += 64; }                                                  \
    __builtin_amdgcn_s_setprio(1);                                          \
    _Pragma("unroll") for (int j = 0; j < 4; j++) {                         \
      MFMA1(a20, b0[j], acc[2][j]); MFMA1(a30, b0[j], acc[3][j]);           \
    }                                                                       \
    __builtin_amdgcn_s_setprio(0);                                          \
    /* ---- phase 3: i=2,3 khalf1 ; NO loads ; boundary drain ---- */       \
    bf16x8 a21 = *(const bf16x8*)(SA1 + aoff[2]);                           \
    bf16x8 a31 = *(const bf16x8*)(SA1 + aoff[3]);                           \
    __builtin_amdgcn_s_setprio(1);                                          \
    _Pragma("unroll") for (int j = 0; j < 4; j++) {                         \
      MFMA1(a21, b1[j], acc[2][j]); MFMA1(a31, b1[j], acc[3][j]);           \
    }                                                                       \
    __builtin_amdgcn_s_setprio(0);                                          \
    __syncthreads();                                                        \
  } while (0)

template <int EPI>
__global__ __launch_bounds__(512) void gemm_bf16_8p(
    const __bf16* __restrict__ A, int lda, long long sAz,
    const __bf16* __restrict__ Bt, int ldb, long long sBz,
    void* __restrict__ C0v, int ldc, long long sCz,
    int K, float alpha)
{
  // A slabs 256x32 (16 KB), B slabs 128x32 (8 KB); x2 k-halves x2 dbuf = 96 KB
  __shared__ __bf16 sA0_0[256 * 32], sA1_0[256 * 32];
  __shared__ __bf16 sB0_0[128 * 32], sB1_0[128 * 32];
  __shared__ __bf16 sA0_1[256 * 32], sA1_1[256 * 32];
  __shared__ __bf16 sB0_1[128 * 32], sB1_1[128 * 32];
  const int tid = threadIdx.x;
  const int wave = tid >> 6, lane = tid & 63;
  int m0, n0;
  swizzle_mn2<4, 256, 128>(m0, n0);
  A  += (size_t)blockIdx.z * sAz;
  Bt += (size_t)blockIdx.z * sBz;

  // staging (global-side XOR pre-swizzle, same involution as frag reads):
  // A: wave stages rows [w*32, w*32+32); B: rows [w*16, w*16+16).
  const int srow = lane >> 2;
  const int skk = 8 * ((lane & 3) ^ ((lane >> 3) & 3));
  const __bf16* pA0 = A + (size_t)(m0 + wave * 32 + srow) * lda + skk;
  const __bf16* pA1 = pA0 + (size_t)16 * lda;
  const __bf16* pB0 = Bt + (size_t)(n0 + wave * 16 + srow) * ldb + skk;
  const int lw = wave * 1024;   // A: 32 rows * 32 elems
  const int lwB = wave * 512;   // B: 16 rows * 32 elems

  // fragment geometry: wave tile 64(m) x 64(n); 4 m-frags, 4 n-frags
  const int fr = lane & 15, fq = lane >> 4;
  const int wm = (wave >> 1) * 64, wn = (wave & 1) * 64;
  int aoff[4], boff[4];
#pragma unroll
  for (int i = 0; i < 4; i++) {
    int rA = wm + i * 16 + fr;
    aoff[i] = rA * 32 + 8 * (fq ^ ((rA >> 1) & 3));
    int rB = wn + i * 16 + fr;
    boff[i] = rB * 32 + 8 * (fq ^ ((rB >> 1) & 3));
  }

  floatx4 acc[4][4];
#pragma unroll
  for (int i = 0; i < 4; i++)
#pragma unroll
    for (int j = 0; j < 4; j++) acc[i][j] = (floatx4){0.f, 0.f, 0.f, 0.f};

  const int ktiles = K >> 6;          // BK=64; must be even

  // prologue: stage tile 0 into set 0
  gll16(pA0, sA0_0 + lw); gll16(pA1, sA0_0 + lw + 512);
  gll16(pA0 + 32, sA1_0 + lw); gll16(pA1 + 32, sA1_0 + lw + 512);
  gll16(pB0, sB0_0 + lwB); gll16(pB0 + 32, sB1_0 + lwB);
  pA0 += 64; pA1 += 64; pB0 += 64;
  __syncthreads();

  for (int it = 0; it < (ktiles >> 1); ++it) {
    PTILE(sA0_0, sA1_0, sB0_0, sB1_0, sA0_1, sA1_1, sB0_1, sB1_1,
          (2 * it + 1 < ktiles));
    PTILE(sA0_1, sA1_1, sB0_1, sB1_1, sA0_0, sA1_0, sB0_0, sB1_0,
          (2 * it + 2 < ktiles));
  }

  // epilogue: C/D map col=lane&15, row=(lane>>4)*4+reg
  const int rb = m0 + wm + fq * 4;
  const int cb = n0 + wn + fr;
#pragma unroll
  for (int i = 0; i < 4; i++) {
#pragma unroll
    for (int j = 0; j < 4; j++) {
      int r = rb + i * 16, c = cb + j * 16;
      float vv[4] = {acc[i][j].x * alpha, acc[i][j].y * alpha,
                     acc[i][j].z * alpha, acc[i][j].w * alpha};
      if (EPI == 0) {
        float* C = (float*)C0v + (size_t)blockIdx.z * sCz;
        float* p = C + (size_t)r * ldc + c;
        p[0] = vv[0]; p[ldc] = vv[1]; p[2 * ldc] = vv[2]; p[3 * ldc] = vv[3];
      } else {  // EPI == 3: bf16 store
        __bf16* C = (__bf16*)C0v + (size_t)blockIdx.z * sCz;
        C[(size_t)r * ldc + c] = (__bf16)vv[0];
        C[(size_t)(r + 1) * ldc + c] = (__bf16)vv[1];
        C[(size_t)(r + 2) * ldc + c] = (__bf16)vv[2];
        C[(size_t)(r + 3) * ldc + c] = (__bf16)vv[3];
      }
    }
  }
}

// ---------------------------------------------------------------------------
// Wave-per-row in-place softmax: f32 row [2048] -> bf16 into same row.
// ---------------------------------------------------------------------------
__global__ __launch_bounds__(256) void softmax_wave(float* __restrict__ Pf)
{
  const int wave = threadIdx.x >> 6, lane = threadIdx.x & 63;
  const size_t row = (size_t)blockIdx.x * 4 + wave;
  float* p = Pf + row * 2048;
  __bf16* q = (__bf16*)p;

  float4 v[8];
  float m = -1e30f;
#pragma unroll
  for (int t = 0; t < 8; t++) {
    v[t] = ((const float4*)p)[lane + t * 64];
    m = fmaxf(m, fmaxf(fmaxf(v[t].x, v[t].y), fmaxf(v[t].z, v[t].w)));
  }
#pragma unroll
  for (int off = 32; off; off >>= 1) m = fmaxf(m, __shfl_xor(m, off, 64));

  float s = 0.f;
#pragma unroll
  for (int t = 0; t < 8; t++) {
    v[t].x = expf(v[t].x - m); v[t].y = expf(v[t].y - m);
    v[t].z = expf(v[t].z - m); v[t].w = expf(v[t].w - m);
    s += (v[t].x + v[t].y) + (v[t].z + v[t].w);
  }
#pragma unroll
  for (int off = 32; off; off >>= 1) s += __shfl_xor(s, off, 64);
  float inv = 1.0f / s;

#pragma unroll
  for (int t = 0; t < 8; t++) {
    bf16x4 o;
    o.x = (__bf16)(v[t].x * inv); o.y = (__bf16)(v[t].y * inv);
    o.z = (__bf16)(v[t].z * inv); o.w = (__bf16)(v[t].w * inv);
    *(bf16x4*)(q + (lane + t * 64) * 4) = o;
  }
}

// ---------------------------------------------------------------------------
extern "C" void kernel_launch(void* const* d_in, const int* in_sizes, int n_in,
                              void* d_out, int out_size, void* d_ws, size_t ws_size,
                              hipStream_t stream)
{
  (void)in_sizes; (void)n_in; (void)out_size; (void)ws_size;
  const float* x     = (const float*)d_in[0];
  const float* blade = (const float*)d_in[1];
  const float* w_q   = (const float*)d_in[2];
  const float* w_k   = (const float*)d_in[3];
  const float* w_v   = (const float*)d_in[4];
  const float* w_o   = (const float*)d_in[5];
  float* out = (float*)d_out;

  // --- fixed aliased workspace plan (peak 234,881,024 B; ws >= 256 MB) -----
  char* base = (char*)d_ws;
  __bf16* wbo   = (__bf16*)(base);                  //  16.78 MB [1024,8192]
  __bf16* vT    = (__bf16*)(base + 16777216);       //   8.39 MB [1024,4096]
  __bf16* qkmh  = (__bf16*)(base + 25165824);       //  37.75 MB [4096,4608]
  __bf16* qkml  = (__bf16*)(base + 62914560);       //  37.75 MB
  char* scr = base + 100663296;
  // phase 1 (aliases Pf region):
  __bf16* xh    = (__bf16*)(scr);                   //   8.39 MB [4096,1024]
  __bf16* xl    = (__bf16*)(scr + 8388608);         //   8.39 MB
  __bf16* wbqkh = (__bf16*)(scr + 16777216);        //   9.44 MB [4608,1024]
  __bf16* wbqkl = (__bf16*)(scr + 26214400);        //   9.44 MB
  __bf16* wbv   = (__bf16*)(scr + 35651584);        //   2.10 MB [1024,1024]
  // phase 2/3:
  float*  Pf    = (float*)(scr);                    //  67.11 MB [4,2048,2048]
  __bf16* A2    = (__bf16*)(scr + 67108864);        //  33.55 MB [2048,8192]
  float*  Part  = (float*)(scr + 100663296);        //  33.55 MB [4,2048,1024]

  dim3 blk(256);
  const float scale = 0.04419417382415922f;  // 1/sqrt(512)

  // --- phase 1: prep + projections ----------------------------------------
  prep2<<<10752, blk, 0, stream>>>(x, blade, w_q, w_k, w_v, w_o,
                                   xh, xl, wbqkh, wbqkl, wbv, wbo);

  // qkm q-part: [4096,1024] x [4096,1024]^T -> cols 0..4095 of qkm.
  // 256^2 8-phase (32x32 MFMA, conflict-free swizzle): grid 16x16 = 1/CU.
  gemm_split_8p<2><<<dim3(16, 16, 1), dim3(512), 0, stream>>>(
      xh, xl, 1024, 0, wbqkh, wbqkl, 1024, 0,
      qkmh, qkml, 4608, 0, 1024, 1.f);

  // qkm km-part: [4096,1024] x [512,1024]^T -> cols 4096..4607 of qkm.
  gemm_split<2><<<dim3(4, 32, 1), blk, 0, stream>>>(
      xh, xl, 1024, 0,
      wbqkh + (size_t)4096 * 1024, wbqkl + (size_t)4096 * 1024, 1024, 0,
      qkmh + 4096, qkml + 4096, 4608, 0, 1024, 1.f);

  // vT = wbv * xh^T : [1024,1024] x [4096,1024]^T -> [1024,4096] bf16
  gemm_bf16<3><<<dim3(32, 8, 1), blk, 0, stream>>>(
      wbv, 1024, 0, xh, 1024, 0, vT, 4096, 0, 1024, 1.f);

  // --- phase 2/3: attention + O-projection per batch -----------------------
  for (int b = 0; b < 2; b++) {
    const __bf16* qh_b  = qkmh + (size_t)b * 2048 * 4608;
    const __bf16* ql_b  = qkml + (size_t)b * 2048 * 4608;
    const __bf16* kmh_b = qh_b + 4096;   // km cols 4096..4607, ldb 4608
    const __bf16* kml_b = ql_b + 4096;

    for (int h0 = 0; h0 < 8; h0 += 4) {
      // scores -> Pf [z,2048,2048] f32 (z = head in group)
      // 8-phase 256^2 tiles (32x32 MFMA): grid 8x8x4 = 256 blocks = 1/CU
      gemm_split_8p<0><<<dim3(8, 8, 4), dim3(512), 0, stream>>>(
          qh_b + h0 * 512, ql_b + h0 * 512, 4608, 512,
          kmh_b, kml_b, 4608, 0,
          Pf, nullptr, 2048, (long long)2048 * 2048, 512, scale);
      // softmax in place: bf16 P into Pf rows (row stride 4096 bf16 units)
      softmax_wave<<<4 * 2048 / 4, blk, 0, stream>>>(Pf);
      // PV: P [z,2048,2048] * vT_b^T -> A2 cols (h0+z)*1024
      // 8-phase 256x128 tiles: grid 8x8x4 = 256 blocks = 1 per CU
      gemm_bf16_8p<3><<<dim3(8, 8, 4), dim3(512), 0, stream>>>(
          (const __bf16*)Pf, 4096, (long long)2048 * 4096,
          vT + (size_t)b * 2048, 4096, 0,
          A2 + (size_t)h0 * 1024, 8192, 1024, 2048, 1.f);
    }

    // O-proj: A2 [2048,8192] x wbo [1024,8192]^T, split-K=4 -> partials
    // 8-phase 256x128 tiles: grid 8x8x4 = 256 blocks = 1 per CU
    gemm_bf16_8p<0><<<dim3(8, 8, 4), dim3(512), 0, stream>>>(
        A2, 8192, 2048, wbo, 8192, 2048,
        Part, 1024, (long long)2048 * 1024, 2048, 1.f);
    reduce4<<<2048, blk, 0, stream>>>(Part, out + (size_t)b * 2048 * 1024,
                                      2048 * 1024);
  }
}

// Round 12
// 715.030 us; speedup vs baseline: 1.0561x; 1.0299x over previous
//
#include <hip/hip_runtime.h>
#include <math.h>

// ---------------------------------------------------------------------------
// GeometricAttentionLayer: B=2, N=2048, C=64, MV=16, D=64, H=8, BLADE=9
// R25: abandon 32x32 MFMA in gemm_split_8p — R24 proved the 4-way bank
// conflict is UNAVOIDABLE in a 32-elem-row LDS layout with 32-row frags
// (bank = 16(r&1)+4key, key has only 2 bits; even rows can't leave quads
// 0-3). Revert gemm_split_8p to R21's 16x16 version (conflict-free,
// barrier-free, qkm-q 83us measured). gemm_bf16_8p PTILE reverts to R20's
// barriered version: R20->R21 A/B showed barrier-free HELPED the fat
// 24-MFMA TILE8P phases (-4us/dispatch) but HURT the thin 8-MFMA PTILE
// phases (~+13us total) — take the best of each, both harness-verified.
// ---------------------------------------------------------------------------

typedef __bf16 bf16x8 __attribute__((ext_vector_type(8)));
typedef __bf16 bf16x4 __attribute__((ext_vector_type(4)));
typedef float floatx4 __attribute__((ext_vector_type(4)));
typedef float floatx16 __attribute__((ext_vector_type(16)));

__constant__ int c_ip[8] = {0, 2, 3, 4, 8, 9, 10, 14};

// ---------------------------------------------------------------------------
// prep2: one block per output row (coalesced, LDS-staged weights).
// ---------------------------------------------------------------------------
__global__ __launch_bounds__(256) void prep2(
    const float* __restrict__ x, const float* __restrict__ blade,
    const float* __restrict__ w_q, const float* __restrict__ w_k,
    const float* __restrict__ w_v, const float* __restrict__ w_o,
    __bf16* __restrict__ xh, __bf16* __restrict__ xl,
    __bf16* __restrict__ wbqkh, __bf16* __restrict__ wbqkl,
    __bf16* __restrict__ wbv, __bf16* __restrict__ wbo)
{
  __shared__ float sw[4608];
  __shared__ float sbl[144];
  const int blk = blockIdx.x;
  const int tid = threadIdx.x;

  if (blk < 4608) {            // ---- wbqk row (hi/lo) ----
    int n = blk;
    const float* wrow;
    int y;
    if (n < 4096) {            // q rows: n = h*512 + d*8 + e ; j = d*8+h
      int e = n & 7, d = (n >> 3) & 63, h = n >> 9;
      wrow = w_q + (size_t)(d * 8 + h) * 576;
      y = c_ip[e];
    } else {                   // k rows: n-4096 = d*8 + e ; j = d
      int n2 = n - 4096;
      int e = n2 & 7, d = n2 >> 3;
      wrow = w_k + (size_t)d * 576;
      y = c_ip[e];
    }
    for (int t = tid; t < 576; t += 256) sw[t] = wrow[t];
    if (tid < 144) sbl[tid] = blade[(tid >> 4) * 256 + (tid & 15) * 16 + y];
    __syncthreads();
#pragma unroll
    for (int kq = 0; kq < 4; kq++) {
      int k = kq * 256 + tid;            // k = i*16 + x
      int i = k >> 4, xx = k & 15;
      float s = 0.f;
#pragma unroll
      for (int b = 0; b < 9; b++) s += sw[i * 9 + b] * sbl[b * 16 + xx];
      __bf16 h16 = (__bf16)s;
      wbqkh[(size_t)n * 1024 + k] = h16;
      wbqkl[(size_t)n * 1024 + k] = (__bf16)(s - (float)h16);
    }
  } else if (blk < 5632) {     // ---- wbv row ----
    int n = blk - 4608;        // n = d*16 + mv ; y = mv
    int d = n >> 4, y = n & 15;
    const float* wrow = w_v + (size_t)d * 576;
    for (int t = tid; t < 576; t += 256) sw[t] = wrow[t];
    if (tid < 144) sbl[tid] = blade[(tid >> 4) * 256 + (tid & 15) * 16 + y];
    __syncthreads();
#pragma unroll
    for (int kq = 0; kq < 4; kq++) {
      int k = kq * 256 + tid;
      int i = k >> 4, xx = k & 15;
      float s = 0.f;
#pragma unroll
      for (int b = 0; b < 9; b++) s += sw[i * 9 + b] * sbl[b * 16 + xx];
      wbv[(size_t)n * 1024 + k] = (__bf16)s;
    }
  } else if (blk < 6656) {     // ---- wbo row ----
    int n = blk - 5632;        // n = c*16 + y
    int c = n >> 4, y = n & 15;
    const float* wrow = w_o + (size_t)c * 4608;   // w_o[c, ich, b]
    for (int t = tid; t < 4608; t += 256) sw[t] = wrow[t];
    if (tid < 144) sbl[tid] = blade[(tid >> 4) * 256 + (tid & 15) * 16 + y];
    __syncthreads();
#pragma unroll
    for (int kq = 0; kq < 32; kq++) {
      int k = kq * 256 + tid;            // k = h*1024 + d*16 + mv
      int ich = (k >> 10) * 64 + ((k >> 4) & 63);
      int mv = k & 15;
      float s = 0.f;
#pragma unroll
      for (int b = 0; b < 9; b++) s += sw[ich * 9 + b] * sbl[b * 16 + mv];
      wbo[(size_t)n * 8192 + k] = (__bf16)s;
    }
  } else {                     // ---- x split (float4) ----
    int idx = (blk - 6656) * 256 + tid;  // over 4096*1024/4
    float4 v = ((const float4*)x)[idx];
    bf16x4 h, l;
    h.x = (__bf16)v.x; l.x = (__bf16)(v.x - (float)h.x);
    h.y = (__bf16)v.y; l.y = (__bf16)(v.y - (float)h.y);
    h.z = (__bf16)v.z; l.z = (__bf16)(v.z - (float)h.z);
    h.w = (__bf16)v.w; l.w = (__bf16)(v.w - (float)h.w);
    *(bf16x4*)(xh + (size_t)idx * 4) = h;
    *(bf16x4*)(xl + (size_t)idx * 4) = l;
  }
}

// sum 4 partial f32 buffers (each n elements) into out
__global__ __launch_bounds__(256) void reduce4(
    const float* __restrict__ p, float* __restrict__ out, int n)
{
  int i = (blockIdx.x * 256 + threadIdx.x) * 4;
  if (i >= n) return;
  float4 a = *(const float4*)(p + i);
  float4 b = *(const float4*)(p + (size_t)n + i);
  float4 c = *(const float4*)(p + 2 * (size_t)n + i);
  float4 d = *(const float4*)(p + 3 * (size_t)n + i);
  *(float4*)(out + i) = make_float4(a.x + b.x + c.x + d.x, a.y + b.y + c.y + d.y,
                                    a.z + b.z + c.z + d.z, a.w + b.w + c.w + d.w);
}

// ---------------------------------------------------------------------------
static __device__ __forceinline__ void gll16(const __bf16* g, __bf16* l) {
  __builtin_amdgcn_global_load_lds(
      (const __attribute__((address_space(1))) void*)g,
      (__attribute__((address_space(3))) void*)l, 16, 0, 0);
}

// GROUP-panel swizzle (L2 locality). TS = tile size in elements (square).
template <int GROUP, int TS>
static __device__ __forceinline__ void swizzle_mn(int& m0, int& n0) {
  int gn = gridDim.x;
  int flat = blockIdx.y * gn + blockIdx.x;
  int panel = flat / (GROUP * gn);
  int r = flat - panel * GROUP * gn;
  m0 = (panel * GROUP + (r % GROUP)) * TS;
  n0 = (r / GROUP) * TS;
}

// Rectangular-tile variant: TSM x TSN tiles (bijective for any grid).
template <int GROUP, int TSM, int TSN>
static __device__ __forceinline__ void swizzle_mn2(int& m0, int& n0) {
  int gn = gridDim.x;
  int flat = blockIdx.y * gn + blockIdx.x;
  int panel = flat / (GROUP * gn);
  int r = flat - panel * GROUP * gn;
  m0 = (panel * GROUP + (r % GROUP)) * TSM;
  n0 = (r / GROUP) * TSN;
}

// LDS slot of (row, logical k16-step t, k-half kh) under the staging swizzle.
static __device__ __forceinline__ int frag_off32(int row, int t, int kh) {
  return row * 32 + 8 * ((2 * t + kh) ^ ((row >> 1) & 3));
}

// ---------------------------------------------------------------------------
// Plain bf16 MFMA GEMM (32x32x16): C = alpha * A * Bt^T. 128x128, BK=32.
// EPI: 0 = f32 store, 3 = bf16 store. z-batched via element strides.
// ---------------------------------------------------------------------------
template <int EPI>
__global__ __launch_bounds__(256) void gemm_bf16(
    const __bf16* __restrict__ A, int lda, long long sAz,
    const __bf16* __restrict__ Bt, int ldb, long long sBz,
    void* __restrict__ C0v, int ldc, long long sCz,
    int K, float alpha)
{
  __shared__ __bf16 As[128 * 32];
  __shared__ __bf16 Bs[128 * 32];
  const int tid = threadIdx.x;
  const int wave = tid >> 6, lane = tid & 63;
  int m0, n0;
  swizzle_mn<4, 128>(m0, n0);
  A  += (size_t)blockIdx.z * sAz;
  Bt += (size_t)blockIdx.z * sBz;

  const int srow = lane >> 2;
  const int skk = 8 * ((lane & 3) ^ ((lane >> 3) & 3));
  const __bf16* gA0 = A  + (size_t)(m0 + wave * 32      + srow) * lda + skk;
  const __bf16* gA1 = A  + (size_t)(m0 + wave * 32 + 16 + srow) * lda + skk;
  const __bf16* gB0 = Bt + (size_t)(n0 + wave * 32      + srow) * ldb + skk;
  const __bf16* gB1 = Bt + (size_t)(n0 + wave * 32 + 16 + srow) * ldb + skk;
  const int ldsoff = wave * 1024;

  const int l31 = lane & 31, kh = lane >> 5;
  const int wm = (wave & 1) * 64, wn = (wave >> 1) * 64;
  int aoff[2][2], boff[2][2];
#pragma unroll
  for (int i = 0; i < 2; i++)
#pragma unroll
    for (int t = 0; t < 2; t++) {
      aoff[i][t] = frag_off32(wm + i * 32 + l31, t, kh);
      boff[i][t] = frag_off32(wn + i * 32 + l31, t, kh);
    }

  floatx16 acc[2][2];
#pragma unroll
  for (int i = 0; i < 2; i++)
#pragma unroll
    for (int j = 0; j < 2; j++)
#pragma unroll
      for (int e = 0; e < 16; e++) acc[i][j][e] = 0.f;

  for (int k0 = 0; k0 < K; k0 += 32) {
    gll16(gA0, As + ldsoff); gll16(gA1, As + ldsoff + 512);
    gll16(gB0, Bs + ldsoff); gll16(gB1, Bs + ldsoff + 512);
    gA0 += 32; gA1 += 32; gB0 += 32; gB1 += 32;
    __syncthreads();
    bf16x8 af[2][2], bfv[2][2];
#pragma unroll
    for (int i = 0; i < 2; i++)
#pragma unroll
      for (int t = 0; t < 2; t++) {
        af[i][t]  = *(const bf16x8*)(As + aoff[i][t]);
        bfv[i][t] = *(const bf16x8*)(Bs + boff[i][t]);
      }
#pragma unroll
    for (int t = 0; t < 2; t++)
#pragma unroll
      for (int i = 0; i < 2; i++)
#pragma unroll
        for (int j = 0; j < 2; j++)
          acc[i][j] = __builtin_amdgcn_mfma_f32_32x32x16_bf16(
              af[i][t], bfv[j][t], acc[i][j], 0, 0, 0);
    __syncthreads();
  }

  // C/D: col = lane&31, row = (reg&3) + 8*(reg>>2) + 4*kh  [m74/m101]
  const int rb = m0 + wm + 4 * kh;
  const int cb = n0 + wn + l31;
#pragma unroll
  for (int i = 0; i < 2; i++) {
#pragma unroll
    for (int j = 0; j < 2; j++) {
      int c = cb + j * 32;
#pragma unroll
      for (int q = 0; q < 4; q++) {
        int r = rb + i * 32 + 8 * q;
        float v0 = acc[i][j][q * 4 + 0] * alpha;
        float v1 = acc[i][j][q * 4 + 1] * alpha;
        float v2 = acc[i][j][q * 4 + 2] * alpha;
        float v3 = acc[i][j][q * 4 + 3] * alpha;
        if (EPI == 0) {
          float* C = (float*)C0v + (size_t)blockIdx.z * sCz;
          float* p = C + (size_t)r * ldc + c;
          p[0] = v0; p[ldc] = v1; p[2 * ldc] = v2; p[3 * ldc] = v3;
        } else {  // EPI == 3: bf16 store
          __bf16* C = (__bf16*)C0v + (size_t)blockIdx.z * sCz;
          C[(size_t)r * ldc + c] = (__bf16)v0;
          C[(size_t)(r + 1) * ldc + c] = (__bf16)v1;
          C[(size_t)(r + 2) * ldc + c] = (__bf16)v2;
          C[(size_t)(r + 3) * ldc + c] = (__bf16)v3;
        }
      }
    }
  }
}

// ---------------------------------------------------------------------------
// Fused split-bf16 GEMM (16x16x32, conflict-free):
// C = alpha * (Ah*Bh^T + Al*Bh^T + Ah*Bl^T). 48 MFMA per 32-k step.
// EPI: 0 = f32 store, 2 = split hi/lo bf16 store. GROUP=8 swizzle.
// ---------------------------------------------------------------------------
template <int EPI>
__global__ __launch_bounds__(256) void gemm_split(
    const __bf16* __restrict__ Ah, const __bf16* __restrict__ Al, int lda, long long sAz,
    const __bf16* __restrict__ Bh, const __bf16* __restrict__ Bl, int ldb, long long sBz,
    void* __restrict__ C0v, void* __restrict__ C1v, int ldc, long long sCz,
    int K, float alpha)
{
  __shared__ __bf16 Ash[128 * 32];
  __shared__ __bf16 Asl[128 * 32];
  __shared__ __bf16 Bsh[128 * 32];
  __shared__ __bf16 Bsl[128 * 32];
  const int tid = threadIdx.x;
  const int wave = tid >> 6, lane = tid & 63;
  int m0, n0;
  swizzle_mn<8, 128>(m0, n0);
  Ah += (size_t)blockIdx.z * sAz;
  Al += (size_t)blockIdx.z * sAz;
  Bh += (size_t)blockIdx.z * sBz;
  Bl += (size_t)blockIdx.z * sBz;

  const int srow = lane >> 2;
  const int skk = 8 * ((lane & 3) ^ ((lane >> 3) & 3));
  const size_t ao0 = (size_t)(m0 + wave * 32      + srow) * lda + skk;
  const size_t ao1 = (size_t)(m0 + wave * 32 + 16 + srow) * lda + skk;
  const size_t bo0 = (size_t)(n0 + wave * 32      + srow) * ldb + skk;
  const size_t bo1 = (size_t)(n0 + wave * 32 + 16 + srow) * ldb + skk;
  const __bf16 *gAh0 = Ah + ao0, *gAh1 = Ah + ao1;
  const __bf16 *gAl0 = Al + ao0, *gAl1 = Al + ao1;
  const __bf16 *gBh0 = Bh + bo0, *gBh1 = Bh + bo1;
  const __bf16 *gBl0 = Bl + bo0, *gBl1 = Bl + bo1;
  const int ldsoff = wave * 1024;

  const int fr = lane & 15, fq = lane >> 4;
  const int wm = (wave & 1) * 64, wn = (wave >> 1) * 64;
  int aoff[4], boff[4];
#pragma unroll
  for (int t = 0; t < 4; t++) {
    int rA = wm + t * 16 + fr;
    aoff[t] = rA * 32 + 8 * (fq ^ ((rA >> 1) & 3));
    int rB = wn + t * 16 + fr;
    boff[t] = rB * 32 + 8 * (fq ^ ((rB >> 1) & 3));
  }

  floatx4 acc[4][4];
#pragma unroll
  for (int i = 0; i < 4; i++)
#pragma unroll
    for (int j = 0; j < 4; j++) acc[i][j] = (floatx4){0.f, 0.f, 0.f, 0.f};

  for (int k0 = 0; k0 < K; k0 += 32) {
    gll16(gAh0, Ash + ldsoff); gll16(gAh1, Ash + ldsoff + 512);
    gll16(gAl0, Asl + ldsoff); gll16(gAl1, Asl + ldsoff + 512);
    gll16(gBh0, Bsh + ldsoff); gll16(gBh1, Bsh + ldsoff + 512);
    gll16(gBl0, Bsl + ldsoff); gll16(gBl1, Bsl + ldsoff + 512);
    gAh0 += 32; gAh1 += 32; gAl0 += 32; gAl1 += 32;
    gBh0 += 32; gBh1 += 32; gBl0 += 32; gBl1 += 32;
    __syncthreads();
    bf16x8 afh[4], afl[4], bfh[4], bfl[4];
#pragma unroll
    for (int t = 0; t < 4; t++) {
      afh[t] = *(const bf16x8*)(Ash + aoff[t]);
      afl[t] = *(const bf16x8*)(Asl + aoff[t]);
      bfh[t] = *(const bf16x8*)(Bsh + boff[t]);
      bfl[t] = *(const bf16x8*)(Bsl + boff[t]);
    }
#pragma unroll
    for (int i = 0; i < 4; i++)
#pragma unroll
      for (int j = 0; j < 4; j++) {
        acc[i][j] = __builtin_amdgcn_mfma_f32_16x16x32_bf16(
            afh[i], bfh[j], acc[i][j], 0, 0, 0);
        acc[i][j] = __builtin_amdgcn_mfma_f32_16x16x32_bf16(
            afl[i], bfh[j], acc[i][j], 0, 0, 0);
        acc[i][j] = __builtin_amdgcn_mfma_f32_16x16x32_bf16(
            afh[i], bfl[j], acc[i][j], 0, 0, 0);
      }
    __syncthreads();
  }

  const int rb = m0 + wm + fq * 4;
  const int cb = n0 + wn + fr;
#pragma unroll
  for (int i = 0; i < 4; i++) {
#pragma unroll
    for (int j = 0; j < 4; j++) {
      float vv[4] = {acc[i][j].x * alpha, acc[i][j].y * alpha,
                     acc[i][j].z * alpha, acc[i][j].w * alpha};
      int r = rb + i * 16, c = cb + j * 16;
      if (EPI == 0) {
        float* C = (float*)C0v + (size_t)blockIdx.z * sCz;
        float* p = C + (size_t)r * ldc + c;
        p[0] = vv[0]; p[ldc] = vv[1]; p[2 * ldc] = vv[2]; p[3 * ldc] = vv[3];
      } else {  // EPI == 2: split hi/lo
        __bf16* Hp = (__bf16*)C0v + (size_t)blockIdx.z * sCz;
        __bf16* Lp = (__bf16*)C1v + (size_t)blockIdx.z * sCz;
#pragma unroll
        for (int t = 0; t < 4; t++) {
          size_t o = (size_t)(r + t) * ldc + c;
          __bf16 hh = (__bf16)vv[t];
          Hp[o] = hh;
          Lp[o] = (__bf16)(vv[t] - (float)hh);
        }
      }
    }
  }
}

// ---------------------------------------------------------------------------
// 8-phase 256x256 split-bf16 GEMM (R21 version, 16x16x32). 8 waves, BK=32,
// 8 STATICALLY DISTINCT LDS buffers. NO mid-tile barriers — waves free-run
// within a K-tile; only the boundary __syncthreads (vmcnt drain) remains.
// Loads paced 3/3/2/0. Conflict-free (measured 0).
// EPI: 0 = f32 store (alpha), 2 = split hi/lo bf16 store.
// ---------------------------------------------------------------------------
#define MFMA1(a, b, c) c = __builtin_amdgcn_mfma_f32_16x16x32_bf16(a, b, c, 0, 0, 0)

#define MFMA_PAIR(i0, i1)                                                   \
  __builtin_amdgcn_s_setprio(1);                                            \
  _Pragma("unroll") for (int j = 0; j < 4; j++) {                           \
    MFMA1(a0h, bh[j], acc[i0][j]); MFMA1(a1h, bh[j], acc[i1][j]);           \
    MFMA1(a0l, bh[j], acc[i0][j]); MFMA1(a1l, bh[j], acc[i1][j]);           \
    MFMA1(a0h, bl[j], acc[i0][j]); MFMA1(a1h, bl[j], acc[i1][j]);           \
  }                                                                         \
  __builtin_amdgcn_s_setprio(0)

#define TILE8P(SAh, SAl, SBh, SBl, DAh, DAl, DBh, DBl, PF)                  \
  do {                                                                      \
    bf16x8 bh[4], bl[4];                                                    \
    _Pragma("unroll") for (int j = 0; j < 4; j++) {                         \
      bh[j] = *(const bf16x8*)(SBh + boff[j]);                              \
      bl[j] = *(const bf16x8*)(SBl + boff[j]);                              \
    }                                                                       \
    /* ---- phase 0: i=0,1 ; prefetch Ah pair + Al first (3) ---- */        \
    bf16x8 a0h = *(const bf16x8*)(SAh + aoff[0]);                           \
    bf16x8 a0l = *(const bf16x8*)(SAl + aoff[0]);                           \
    bf16x8 a1h = *(const bf16x8*)(SAh + aoff[1]);                           \
    bf16x8 a1l = *(const bf16x8*)(SAl + aoff[1]);                           \
    if (PF) { gll16(pAh0, DAh + lw); gll16(pAh1, DAh + lw + 512);           \
              gll16(pAl0, DAl + lw);                                        \
              pAh0 += 32; pAh1 += 32; pAl0 += 32; }                         \
    MFMA_PAIR(0, 1);                                                        \
    /* ---- phase 1: i=2,3 ; prefetch Al second + Bh pair (3) ---- */       \
    a0h = *(const bf16x8*)(SAh + aoff[2]);                                  \
    a0l = *(const bf16x8*)(SAl + aoff[2]);                                  \
    a1h = *(const bf16x8*)(SAh + aoff[3]);                                  \
    a1l = *(const bf16x8*)(SAl + aoff[3]);                                  \
    if (PF) { gll16(pAl1, DAl + lw + 512);                                  \
              gll16(pBh0, DBh + lw); gll16(pBh1, DBh + lw + 512);           \
              pAl1 += 32; pBh0 += 32; pBh1 += 32; }                         \
    MFMA_PAIR(2, 3);                                                        \
    /* ---- phase 2: i=4,5 ; prefetch Bl pair (2) ---- */                   \
    a0h = *(const bf16x8*)(SAh + aoff[4]);                                  \
    a0l = *(const bf16x8*)(SAl + aoff[4]);                                  \
    a1h = *(const bf16x8*)(SAh + aoff[5]);                                  \
    a1l = *(const bf16x8*)(SAl + aoff[5]);                                  \
    if (PF) { gll16(pBl0, DBl + lw); gll16(pBl1, DBl + lw + 512);           \
              pBl0 += 32; pBl1 += 32; }                                     \
    MFMA_PAIR(4, 5);                                                        \
    /* ---- phase 3: i=6,7 ; NO loads ; boundary drain ---- */              \
    a0h = *(const bf16x8*)(SAh + aoff[6]);                                  \
    a0l = *(const bf16x8*)(SAl + aoff[6]);                                  \
    a1h = *(const bf16x8*)(SAh + aoff[7]);                                  \
    a1l = *(const bf16x8*)(SAl + aoff[7]);                                  \
    MFMA_PAIR(6, 7);                                                        \
    __syncthreads();                                                        \
  } while (0)

template <int EPI>
__global__ __launch_bounds__(512) void gemm_split_8p(
    const __bf16* __restrict__ Ah, const __bf16* __restrict__ Al, int lda, long long sAz,
    const __bf16* __restrict__ Bh, const __bf16* __restrict__ Bl, int ldb, long long sBz,
    void* __restrict__ C0v, void* __restrict__ C1v, int ldc, long long sCz,
    int K, float alpha)
{
  // 8 statically distinct buffers: [4 matrices] x [double buffer], 16 KB each
  __shared__ __bf16 sAh0[256 * 32], sAl0[256 * 32], sBh0[256 * 32], sBl0[256 * 32];
  __shared__ __bf16 sAh1[256 * 32], sAl1[256 * 32], sBh1[256 * 32], sBl1[256 * 32];
  const int tid = threadIdx.x;
  const int wave = tid >> 6, lane = tid & 63;
  int m0, n0;
  swizzle_mn<4, 256>(m0, n0);
  Ah += (size_t)blockIdx.z * sAz;
  Al += (size_t)blockIdx.z * sAz;
  Bh += (size_t)blockIdx.z * sBz;
  Bl += (size_t)blockIdx.z * sBz;

  // staging: wave w loads rows [w*32, w*32+32) of each matrix k-slab,
  // pre-swizzled on the global side (same involution as the fragment reads)
  const int srow = lane >> 2;
  const int skk = 8 * ((lane & 3) ^ ((lane >> 3) & 3));
  const __bf16* pAh0 = Ah + (size_t)(m0 + wave * 32 + srow) * lda + skk;
  const __bf16* pAh1 = pAh0 + (size_t)16 * lda;
  const __bf16* pAl0 = Al + (size_t)(m0 + wave * 32 + srow) * lda + skk;
  const __bf16* pAl1 = pAl0 + (size_t)16 * lda;
  const __bf16* pBh0 = Bh + (size_t)(n0 + wave * 32 + srow) * ldb + skk;
  const __bf16* pBh1 = pBh0 + (size_t)16 * ldb;
  const __bf16* pBl0 = Bl + (size_t)(n0 + wave * 32 + srow) * ldb + skk;
  const __bf16* pBl1 = pBl0 + (size_t)16 * ldb;
  const int lw = wave * 1024;   // 32 rows * 32 elems per wave

  // fragment geometry: wave tile 128(m) x 64(n); 8 m-frags, 4 n-frags
  const int fr = lane & 15, fq = lane >> 4;
  const int wm = (wave >> 2) * 128, wn = (wave & 3) * 64;
  int aoff[8], boff[4];
#pragma unroll
  for (int i = 0; i < 8; i++) {
    int rA = wm + i * 16 + fr;
    aoff[i] = rA * 32 + 8 * (fq ^ ((rA >> 1) & 3));
  }
#pragma unroll
  for (int j = 0; j < 4; j++) {
    int rB = wn + j * 16 + fr;
    boff[j] = rB * 32 + 8 * (fq ^ ((rB >> 1) & 3));
  }

  floatx4 acc[8][4];
#pragma unroll
  for (int i = 0; i < 8; i++)
#pragma unroll
    for (int j = 0; j < 4; j++) acc[i][j] = (floatx4){0.f, 0.f, 0.f, 0.f};

  const int ktiles = K >> 5;          // must be even

  // prologue: stage tile 0 into set 0
  gll16(pAh0, sAh0 + lw); gll16(pAh1, sAh0 + lw + 512); pAh0 += 32; pAh1 += 32;
  gll16(pAl0, sAl0 + lw); gll16(pAl1, sAl0 + lw + 512); pAl0 += 32; pAl1 += 32;
  gll16(pBh0, sBh0 + lw); gll16(pBh1, sBh0 + lw + 512); pBh0 += 32; pBh1 += 32;
  gll16(pBl0, sBl0 + lw); gll16(pBl1, sBl0 + lw + 512); pBl0 += 32; pBl1 += 32;
  __syncthreads();

  for (int it = 0; it < (ktiles >> 1); ++it) {
    TILE8P(sAh0, sAl0, sBh0, sBl0, sAh1, sAl1, sBh1, sBl1,
           (2 * it + 1 < ktiles));
    TILE8P(sAh1, sAl1, sBh1, sBl1, sAh0, sAl0, sBh0, sBl0,
           (2 * it + 2 < ktiles));
  }

  // epilogue: C/D map col=lane&15, row=(lane>>4)*4+reg
  const int rb = m0 + wm + fq * 4;
  const int cb = n0 + wn + fr;
#pragma unroll
  for (int i = 0; i < 8; i++) {
#pragma unroll
    for (int j = 0; j < 4; j++) {
      int r = rb + i * 16, c = cb + j * 16;
      float vv[4] = {acc[i][j].x * alpha, acc[i][j].y * alpha,
                     acc[i][j].z * alpha, acc[i][j].w * alpha};
      if (EPI == 0) {
        float* C = (float*)C0v + (size_t)blockIdx.z * sCz;
        float* p = C + (size_t)r * ldc + c;
        p[0] = vv[0]; p[ldc] = vv[1]; p[2 * ldc] = vv[2]; p[3 * ldc] = vv[3];
      } else {  // EPI == 2: split hi/lo bf16
        __bf16* Hp = (__bf16*)C0v + (size_t)blockIdx.z * sCz;
        __bf16* Lp = (__bf16*)C1v + (size_t)blockIdx.z * sCz;
#pragma unroll
        for (int t = 0; t < 4; t++) {
          size_t o = (size_t)(r + t) * ldc + c;
          __bf16 hh = (__bf16)vv[t];
          Hp[o] = hh;
          Lp[o] = (__bf16)(vv[t] - (float)hh);
        }
      }
    }
  }
}

// ---------------------------------------------------------------------------
// 8-phase plain-bf16 GEMM (R20 version), tile 256(m) x 128(n), BK=64 as two
// 32-k slabs. 4 phases of 8 MFMA WITH mid-tile s_barriers (thin phases
// need the lockstep per R20/R21 A/B); loads 2/2/2/0; one __syncthreads per
// K-tile. 8 waves as 4Mx2N (64x64/wave), acc[4][4]; 96 KB LDS.
// EPI: 0 = f32 store, 3 = bf16 store.
// ---------------------------------------------------------------------------
#define PTILE(SA0, SA1, SB0, SB1, DA0, DA1, DB0, DB1, PF)                   \
  do {                                                                      \
    /* ---- phase 0: b0 frags + i=0,1 khalf0 ; 2 A loads ---- */            \
    bf16x8 b0[4], b1[4];                                                    \
    _Pragma("unroll") for (int j = 0; j < 4; j++)                           \
      b0[j] = *(const bf16x8*)(SB0 + boff[j]);                              \
    bf16x8 a00 = *(const bf16x8*)(SA0 + aoff[0]);                           \
    bf16x8 a10 = *(const bf16x8*)(SA0 + aoff[1]);                           \
    if (PF) { gll16(pA0, DA0 + lw); gll16(pA1, DA0 + lw + 512); }           \
    __builtin_amdgcn_s_setprio(1);                                          \
    _Pragma("unroll") for (int j = 0; j < 4; j++) {                         \
      MFMA1(a00, b0[j], acc[0][j]); MFMA1(a10, b0[j], acc[1][j]);           \
    }                                                                       \
    __builtin_amdgcn_s_setprio(0);                                          \
    __builtin_amdgcn_s_barrier();                                           \
    /* ---- phase 1: b1 frags + i=0,1 khalf1 ; 2 A loads ---- */            \
    _Pragma("unroll") for (int j = 0; j < 4; j++)                           \
      b1[j] = *(const bf16x8*)(SB1 + boff[j]);                              \
    bf16x8 a01 = *(const bf16x8*)(SA1 + aoff[0]);                           \
    bf16x8 a11 = *(const bf16x8*)(SA1 + aoff[1]);                           \
    if (PF) { gll16(pA0 + 32, DA1 + lw); gll16(pA1 + 32, DA1 + lw + 512);   \
              pA0 += 64; pA1 += 64; }                                       \
    __builtin_amdgcn_s_setprio(1);                                          \
    _Pragma("unroll") for (int j = 0; j < 4; j++) {                         \
      MFMA1(a01, b1[j], acc[0][j]); MFMA1(a11, b1[j], acc[1][j]);           \
    }                                                                       \
    __builtin_amdgcn_s_setprio(0);                                          \
    __builtin_amdgcn_s_barrier();                                           \
    /* ---- phase 2: i=2,3 khalf0 ; 2 B loads ---- */                       \
    bf16x8 a20 = *(const bf16x8*)(SA0 + aoff[2]);                           \
    bf16x8 a30 = *(const bf16x8*)(SA0 + aoff[3]);                           \
    if (PF) { gll16(pB0, DB0 + lwB); gll16(pB0 + 32, DB1 + lwB);            \
              pB0 += 64; }                                                  \
    __builtin_amdgcn_s_setprio(1);                                          \
    _Pragma("unroll") for (int j = 0; j < 4; j++) {                         \
      MFMA1(a20, b0[j], acc[2][j]); MFMA1(a30, b0[j], acc[3][j]);           \
    }                                                                       \
    __builtin_amdgcn_s_setprio(0);                                          \
    __builtin_amdgcn_s_barrier();                                           \
    /* ---- phase 3: i=2,3 khalf1 ; NO loads ; boundary drain ---- */       \
    bf16x8 a21 = *(const bf16x8*)(SA1 + aoff[2]);                           \
    bf16x8 a31 = *(const bf16x8*)(SA1 + aoff[3]);                           \
    __builtin_amdgcn_s_setprio(1);                                          \
    _Pragma("unroll") for (int j = 0; j < 4; j++) {                         \
      MFMA1(a21, b1[j], acc[2][j]); MFMA1(a31, b1[j], acc[3][j]);           \
    }                                                                       \
    __builtin_amdgcn_s_setprio(0);                                          \
    __syncthreads();                                                        \
  } while (0)

template <int EPI>
__global__ __launch_bounds__(512) void gemm_bf16_8p(
    const __bf16* __restrict__ A, int lda, long long sAz,
    const __bf16* __restrict__ Bt, int ldb, long long sBz,
    void* __restrict__ C0v, int ldc, long long sCz,
    int K, float alpha)
{
  // A slabs 256x32 (16 KB), B slabs 128x32 (8 KB); x2 k-halves x2 dbuf = 96 KB
  __shared__ __bf16 sA0_0[256 * 32], sA1_0[256 * 32];
  __shared__ __bf16 sB0_0[128 * 32], sB1_0[128 * 32];
  __shared__ __bf16 sA0_1[256 * 32], sA1_1[256 * 32];
  __shared__ __bf16 sB0_1[128 * 32], sB1_1[128 * 32];
  const int tid = threadIdx.x;
  const int wave = tid >> 6, lane = tid & 63;
  int m0, n0;
  swizzle_mn2<4, 256, 128>(m0, n0);
  A  += (size_t)blockIdx.z * sAz;
  Bt += (size_t)blockIdx.z * sBz;

  // staging (global-side XOR pre-swizzle, same involution as frag reads):
  // A: wave stages rows [w*32, w*32+32); B: rows [w*16, w*16+16).
  const int srow = lane >> 2;
  const int skk = 8 * ((lane & 3) ^ ((lane >> 3) & 3));
  const __bf16* pA0 = A + (size_t)(m0 + wave * 32 + srow) * lda + skk;
  const __bf16* pA1 = pA0 + (size_t)16 * lda;
  const __bf16* pB0 = Bt + (size_t)(n0 + wave * 16 + srow) * ldb + skk;
  const int lw = wave * 1024;   // A: 32 rows * 32 elems
  const int lwB = wave * 512;   // B: 16 rows * 32 elems

  // fragment geometry: wave tile 64(m) x 64(n); 4 m-frags, 4 n-frags
  const int fr = lane & 15, fq = lane >> 4;
  const int wm = (wave >> 1) * 64, wn = (wave & 1) * 64;
  int aoff[4], boff[4];
#pragma unroll
  for (int i = 0; i < 4; i++) {
    int rA = wm + i * 16 + fr;
    aoff[i] = rA * 32 + 8 * (fq ^ ((rA >> 1) & 3));
    int rB = wn + i * 16 + fr;
    boff[i] = rB * 32 + 8 * (fq ^ ((rB >> 1) & 3));
  }

  floatx4 acc[4][4];
#pragma unroll
  for (int i = 0; i < 4; i++)
#pragma unroll
    for (int j = 0; j < 4; j++) acc[i][j] = (floatx4){0.f, 0.f, 0.f, 0.f};

  const int ktiles = K >> 6;          // BK=64; must be even

  // prologue: stage tile 0 into set 0
  gll16(pA0, sA0_0 + lw); gll16(pA1, sA0_0 + lw + 512);
  gll16(pA0 + 32, sA1_0 + lw); gll16(pA1 + 32, sA1_0 + lw + 512);
  gll16(pB0, sB0_0 + lwB); gll16(pB0 + 32, sB1_0 + lwB);
  pA0 += 64; pA1 += 64; pB0 += 64;
  __syncthreads();

  for (int it = 0; it < (ktiles >> 1); ++it) {
    PTILE(sA0_0, sA1_0, sB0_0, sB1_0, sA0_1, sA1_1, sB0_1, sB1_1,
          (2 * it + 1 < ktiles));
    PTILE(sA0_1, sA1_1, sB0_1, sB1_1, sA0_0, sA1_0, sB0_0, sB1_0,
          (2 * it + 2 < ktiles));
  }

  // epilogue: C/D map col=lane&15, row=(lane>>4)*4+reg
  const int rb = m0 + wm + fq * 4;
  const int cb = n0 + wn + fr;
#pragma unroll
  for (int i = 0; i < 4; i++) {
#pragma unroll
    for (int j = 0; j < 4; j++) {
      int r = rb + i * 16, c = cb + j * 16;
      float vv[4] = {acc[i][j].x * alpha, acc[i][j].y * alpha,
                     acc[i][j].z * alpha, acc[i][j].w * alpha};
      if (EPI == 0) {
        float* C = (float*)C0v + (size_t)blockIdx.z * sCz;
        float* p = C + (size_t)r * ldc + c;
        p[0] = vv[0]; p[ldc] = vv[1]; p[2 * ldc] = vv[2]; p[3 * ldc] = vv[3];
      } else {  // EPI == 3: bf16 store
        __bf16* C = (__bf16*)C0v + (size_t)blockIdx.z * sCz;
        C[(size_t)r * ldc + c] = (__bf16)vv[0];
        C[(size_t)(r + 1) * ldc + c] = (__bf16)vv[1];
        C[(size_t)(r + 2) * ldc + c] = (__bf16)vv[2];
        C[(size_t)(r + 3) * ldc + c] = (__bf16)vv[3];
      }
    }
  }
}

// ---------------------------------------------------------------------------
// Wave-per-row in-place softmax: f32 row [2048] -> bf16 into same row.
// ---------------------------------------------------------------------------
__global__ __launch_bounds__(256) void softmax_wave(float* __restrict__ Pf)
{
  const int wave = threadIdx.x >> 6, lane = threadIdx.x & 63;
  const size_t row = (size_t)blockIdx.x * 4 + wave;
  float* p = Pf + row * 2048;
  __bf16* q = (__bf16*)p;

  float4 v[8];
  float m = -1e30f;
#pragma unroll
  for (int t = 0; t < 8; t++) {
    v[t] = ((const float4*)p)[lane + t * 64];
    m = fmaxf(m, fmaxf(fmaxf(v[t].x, v[t].y), fmaxf(v[t].z, v[t].w)));
  }
#pragma unroll
  for (int off = 32; off; off >>= 1) m = fmaxf(m, __shfl_xor(m, off, 64));

  float s = 0.f;
#pragma unroll
  for (int t = 0; t < 8; t++) {
    v[t].x = expf(v[t].x - m); v[t].y = expf(v[t].y - m);
    v[t].z = expf(v[t].z - m); v[t].w = expf(v[t].w - m);
    s += (v[t].x + v[t].y) + (v[t].z + v[t].w);
  }
#pragma unroll
  for (int off = 32; off; off >>= 1) s += __shfl_xor(s, off, 64);
  float inv = 1.0f / s;

#pragma unroll
  for (int t = 0; t < 8; t++) {
    bf16x4 o;
    o.x = (__bf16)(v[t].x * inv); o.y = (__bf16)(v[t].y * inv);
    o.z = (__bf16)(v[t].z * inv); o.w = (__bf16)(v[t].w * inv);
    *(bf16x4*)(q + (lane + t * 64) * 4) = o;
  }
}

// ---------------------------------------------------------------------------
extern "C" void kernel_launch(void* const* d_in, const int* in_sizes, int n_in,
                              void* d_out, int out_size, void* d_ws, size_t ws_size,
                              hipStream_t stream)
{
  (void)in_sizes; (void)n_in; (void)out_size; (void)ws_size;
  const float* x     = (const float*)d_in[0];
  const float* blade = (const float*)d_in[1];
  const float* w_q   = (const float*)d_in[2];
  const float* w_k   = (const float*)d_in[3];
  const float* w_v   = (const float*)d_in[4];
  const float* w_o   = (const float*)d_in[5];
  float* out = (float*)d_out;

  // --- fixed aliased workspace plan (peak 234,881,024 B; ws >= 256 MB) -----
  char* base = (char*)d_ws;
  __bf16* wbo   = (__bf16*)(base);                  //  16.78 MB [1024,8192]
  __bf16* vT    = (__bf16*)(base + 16777216);       //   8.39 MB [1024,4096]
  __bf16* qkmh  = (__bf16*)(base + 25165824);       //  37.75 MB [4096,4608]
  __bf16* qkml  = (__bf16*)(base + 62914560);       //  37.75 MB
  char* scr = base + 100663296;
  // phase 1 (aliases Pf region):
  __bf16* xh    = (__bf16*)(scr);                   //   8.39 MB [4096,1024]
  __bf16* xl    = (__bf16*)(scr + 8388608);         //   8.39 MB
  __bf16* wbqkh = (__bf16*)(scr + 16777216);        //   9.44 MB [4608,1024]
  __bf16* wbqkl = (__bf16*)(scr + 26214400);        //   9.44 MB
  __bf16* wbv   = (__bf16*)(scr + 35651584);        //   2.10 MB [1024,1024]
  // phase 2/3:
  float*  Pf    = (float*)(scr);                    //  67.11 MB [4,2048,2048]
  __bf16* A2    = (__bf16*)(scr + 67108864);        //  33.55 MB [2048,8192]
  float*  Part  = (float*)(scr + 100663296);        //  33.55 MB [4,2048,1024]

  dim3 blk(256);
  const float scale = 0.04419417382415922f;  // 1/sqrt(512)

  // --- phase 1: prep + projections ----------------------------------------
  prep2<<<10752, blk, 0, stream>>>(x, blade, w_q, w_k, w_v, w_o,
                                   xh, xl, wbqkh, wbqkl, wbv, wbo);

  // qkm q-part: [4096,1024] x [4096,1024]^T -> cols 0..4095 of qkm.
  // 256^2 8-phase: grid 16x16 = 256 blocks = exactly 1 per CU.
  gemm_split_8p<2><<<dim3(16, 16, 1), dim3(512), 0, stream>>>(
      xh, xl, 1024, 0, wbqkh, wbqkl, 1024, 0,
      qkmh, qkml, 4608, 0, 1024, 1.f);

  // qkm km-part: [4096,1024] x [512,1024]^T -> cols 4096..4607 of qkm.
  gemm_split<2><<<dim3(4, 32, 1), blk, 0, stream>>>(
      xh, xl, 1024, 0,
      wbqkh + (size_t)4096 * 1024, wbqkl + (size_t)4096 * 1024, 1024, 0,
      qkmh + 4096, qkml + 4096, 4608, 0, 1024, 1.f);

  // vT = wbv * xh^T : [1024,1024] x [4096,1024]^T -> [1024,4096] bf16
  gemm_bf16<3><<<dim3(32, 8, 1), blk, 0, stream>>>(
      wbv, 1024, 0, xh, 1024, 0, vT, 4096, 0, 1024, 1.f);

  // --- phase 2/3: attention + O-projection per batch -----------------------
  for (int b = 0; b < 2; b++) {
    const __bf16* qh_b  = qkmh + (size_t)b * 2048 * 4608;
    const __bf16* ql_b  = qkml + (size_t)b * 2048 * 4608;
    const __bf16* kmh_b = qh_b + 4096;   // km cols 4096..4607, ldb 4608
    const __bf16* kml_b = ql_b + 4096;

    for (int h0 = 0; h0 < 8; h0 += 4) {
      // scores -> Pf [z,2048,2048] f32 (z = head in group)
      // 8-phase 256^2 tiles: grid 8x8x4 = 256 blocks = exactly 1 per CU
      gemm_split_8p<0><<<dim3(8, 8, 4), dim3(512), 0, stream>>>(
          qh_b + h0 * 512, ql_b + h0 * 512, 4608, 512,
          kmh_b, kml_b, 4608, 0,
          Pf, nullptr, 2048, (long long)2048 * 2048, 512, scale);
      // softmax in place: bf16 P into Pf rows (row stride 4096 bf16 units)
      softmax_wave<<<4 * 2048 / 4, blk, 0, stream>>>(Pf);
      // PV: P [z,2048,2048] * vT_b^T -> A2 cols (h0+z)*1024
      // 8-phase 256x128 tiles: grid 8x8x4 = 256 blocks = 1 per CU
      gemm_bf16_8p<3><<<dim3(8, 8, 4), dim3(512), 0, stream>>>(
          (const __bf16*)Pf, 4096, (long long)2048 * 4096,
          vT + (size_t)b * 2048, 4096, 0,
          A2 + (size_t)h0 * 1024, 8192, 1024, 2048, 1.f);
    }

    // O-proj: A2 [2048,8192] x wbo [1024,8192]^T, split-K=4 -> partials
    // 8-phase 256x128 tiles: grid 8x8x4 = 256 blocks = 1 per CU
    gemm_bf16_8p<0><<<dim3(8, 8, 4), dim3(512), 0, stream>>>(
        A2, 8192, 2048, wbo, 8192, 2048,
        Part, 1024, (long long)2048 * 1024, 2048, 1.f);
    reduce4<<<2048, blk, 0, stream>>>(Part, out + (size_t)b * 2048 * 1024,
                                      2048 * 1024);
  }
}

// Round 13
// 712.987 us; speedup vs baseline: 1.0592x; 1.0029x over previous
//
#include <hip/hip_runtime.h>
#include <math.h>

// ---------------------------------------------------------------------------
// GeometricAttentionLayer: B=2, N=2048, C=64, MV=16, D=64, H=8, BLADE=9
// R26: R25 (best, 715us) + split-K=2 for qkm-km. The km GEMM ran 128
// blocks on 256 CUs (half fill, ~34us). Now: gemm_split<0> with z=2
// (sAz=sBz=512 k-offsets), grid 4x32x2 = 256 blocks = exact fill, f32
// partials into phase-1 scratch (aliases unused Pf space), then split2km
// sums partials and emits hi/lo bf16 into qkm cols 4096+. Extra ~25MB
// traffic (~4us) vs halved GEMM time (~34 -> ~18). All else = R25.
// ---------------------------------------------------------------------------

typedef __bf16 bf16x8 __attribute__((ext_vector_type(8)));
typedef __bf16 bf16x4 __attribute__((ext_vector_type(4)));
typedef float floatx4 __attribute__((ext_vector_type(4)));
typedef float floatx16 __attribute__((ext_vector_type(16)));

__constant__ int c_ip[8] = {0, 2, 3, 4, 8, 9, 10, 14};

// ---------------------------------------------------------------------------
// prep2: one block per output row (coalesced, LDS-staged weights).
// ---------------------------------------------------------------------------
__global__ __launch_bounds__(256) void prep2(
    const float* __restrict__ x, const float* __restrict__ blade,
    const float* __restrict__ w_q, const float* __restrict__ w_k,
    const float* __restrict__ w_v, const float* __restrict__ w_o,
    __bf16* __restrict__ xh, __bf16* __restrict__ xl,
    __bf16* __restrict__ wbqkh, __bf16* __restrict__ wbqkl,
    __bf16* __restrict__ wbv, __bf16* __restrict__ wbo)
{
  __shared__ float sw[4608];
  __shared__ float sbl[144];
  const int blk = blockIdx.x;
  const int tid = threadIdx.x;

  if (blk < 4608) {            // ---- wbqk row (hi/lo) ----
    int n = blk;
    const float* wrow;
    int y;
    if (n < 4096) {            // q rows: n = h*512 + d*8 + e ; j = d*8+h
      int e = n & 7, d = (n >> 3) & 63, h = n >> 9;
      wrow = w_q + (size_t)(d * 8 + h) * 576;
      y = c_ip[e];
    } else {                   // k rows: n-4096 = d*8 + e ; j = d
      int n2 = n - 4096;
      int e = n2 & 7, d = n2 >> 3;
      wrow = w_k + (size_t)d * 576;
      y = c_ip[e];
    }
    for (int t = tid; t < 576; t += 256) sw[t] = wrow[t];
    if (tid < 144) sbl[tid] = blade[(tid >> 4) * 256 + (tid & 15) * 16 + y];
    __syncthreads();
#pragma unroll
    for (int kq = 0; kq < 4; kq++) {
      int k = kq * 256 + tid;            // k = i*16 + x
      int i = k >> 4, xx = k & 15;
      float s = 0.f;
#pragma unroll
      for (int b = 0; b < 9; b++) s += sw[i * 9 + b] * sbl[b * 16 + xx];
      __bf16 h16 = (__bf16)s;
      wbqkh[(size_t)n * 1024 + k] = h16;
      wbqkl[(size_t)n * 1024 + k] = (__bf16)(s - (float)h16);
    }
  } else if (blk < 5632) {     // ---- wbv row ----
    int n = blk - 4608;        // n = d*16 + mv ; y = mv
    int d = n >> 4, y = n & 15;
    const float* wrow = w_v + (size_t)d * 576;
    for (int t = tid; t < 576; t += 256) sw[t] = wrow[t];
    if (tid < 144) sbl[tid] = blade[(tid >> 4) * 256 + (tid & 15) * 16 + y];
    __syncthreads();
#pragma unroll
    for (int kq = 0; kq < 4; kq++) {
      int k = kq * 256 + tid;
      int i = k >> 4, xx = k & 15;
      float s = 0.f;
#pragma unroll
      for (int b = 0; b < 9; b++) s += sw[i * 9 + b] * sbl[b * 16 + xx];
      wbv[(size_t)n * 1024 + k] = (__bf16)s;
    }
  } else if (blk < 6656) {     // ---- wbo row ----
    int n = blk - 5632;        // n = c*16 + y
    int c = n >> 4, y = n & 15;
    const float* wrow = w_o + (size_t)c * 4608;   // w_o[c, ich, b]
    for (int t = tid; t < 4608; t += 256) sw[t] = wrow[t];
    if (tid < 144) sbl[tid] = blade[(tid >> 4) * 256 + (tid & 15) * 16 + y];
    __syncthreads();
#pragma unroll
    for (int kq = 0; kq < 32; kq++) {
      int k = kq * 256 + tid;            // k = h*1024 + d*16 + mv
      int ich = (k >> 10) * 64 + ((k >> 4) & 63);
      int mv = k & 15;
      float s = 0.f;
#pragma unroll
      for (int b = 0; b < 9; b++) s += sw[ich * 9 + b] * sbl[b * 16 + mv];
      wbo[(size_t)n * 8192 + k] = (__bf16)s;
    }
  } else {                     // ---- x split (float4) ----
    int idx = (blk - 6656) * 256 + tid;  // over 4096*1024/4
    float4 v = ((const float4*)x)[idx];
    bf16x4 h, l;
    h.x = (__bf16)v.x; l.x = (__bf16)(v.x - (float)h.x);
    h.y = (__bf16)v.y; l.y = (__bf16)(v.y - (float)h.y);
    h.z = (__bf16)v.z; l.z = (__bf16)(v.z - (float)h.z);
    h.w = (__bf16)v.w; l.w = (__bf16)(v.w - (float)h.w);
    *(bf16x4*)(xh + (size_t)idx * 4) = h;
    *(bf16x4*)(xl + (size_t)idx * 4) = l;
  }
}

// sum 4 partial f32 buffers (each n elements) into out
__global__ __launch_bounds__(256) void reduce4(
    const float* __restrict__ p, float* __restrict__ out, int n)
{
  int i = (blockIdx.x * 256 + threadIdx.x) * 4;
  if (i >= n) return;
  float4 a = *(const float4*)(p + i);
  float4 b = *(const float4*)(p + (size_t)n + i);
  float4 c = *(const float4*)(p + 2 * (size_t)n + i);
  float4 d = *(const float4*)(p + 3 * (size_t)n + i);
  *(float4*)(out + i) = make_float4(a.x + b.x + c.x + d.x, a.y + b.y + c.y + d.y,
                                    a.z + b.z + c.z + d.z, a.w + b.w + c.w + d.w);
}

// R26: sum 2 f32 partial buffers [4096,512] and emit split hi/lo bf16 into
// qkm cols 4096..4607 (ldc 4608). Coalesced float4 in, bf16x4 out.
__global__ __launch_bounds__(256) void split2km(
    const float* __restrict__ p, __bf16* __restrict__ Hp,
    __bf16* __restrict__ Lp)
{
  const int n = 4096 * 512;
  int i = (blockIdx.x * 256 + threadIdx.x) * 4;
  if (i >= n) return;
  float4 a = *(const float4*)(p + i);
  float4 b = *(const float4*)(p + (size_t)n + i);
  float s0 = a.x + b.x, s1 = a.y + b.y, s2 = a.z + b.z, s3 = a.w + b.w;
  int row = i >> 9, col = i & 511;          // 512 cols per row
  size_t o = (size_t)row * 4608 + col;
  bf16x4 h, l;
  h.x = (__bf16)s0; l.x = (__bf16)(s0 - (float)h.x);
  h.y = (__bf16)s1; l.y = (__bf16)(s1 - (float)h.y);
  h.z = (__bf16)s2; l.z = (__bf16)(s2 - (float)h.z);
  h.w = (__bf16)s3; l.w = (__bf16)(s3 - (float)h.w);
  *(bf16x4*)(Hp + o) = h;
  *(bf16x4*)(Lp + o) = l;
}

// ---------------------------------------------------------------------------
static __device__ __forceinline__ void gll16(const __bf16* g, __bf16* l) {
  __builtin_amdgcn_global_load_lds(
      (const __attribute__((address_space(1))) void*)g,
      (__attribute__((address_space(3))) void*)l, 16, 0, 0);
}

// GROUP-panel swizzle (L2 locality). TS = tile size in elements (square).
template <int GROUP, int TS>
static __device__ __forceinline__ void swizzle_mn(int& m0, int& n0) {
  int gn = gridDim.x;
  int flat = blockIdx.y * gn + blockIdx.x;
  int panel = flat / (GROUP * gn);
  int r = flat - panel * GROUP * gn;
  m0 = (panel * GROUP + (r % GROUP)) * TS;
  n0 = (r / GROUP) * TS;
}

// Rectangular-tile variant: TSM x TSN tiles (bijective for any grid).
template <int GROUP, int TSM, int TSN>
static __device__ __forceinline__ void swizzle_mn2(int& m0, int& n0) {
  int gn = gridDim.x;
  int flat = blockIdx.y * gn + blockIdx.x;
  int panel = flat / (GROUP * gn);
  int r = flat - panel * GROUP * gn;
  m0 = (panel * GROUP + (r % GROUP)) * TSM;
  n0 = (r / GROUP) * TSN;
}

// LDS slot of (row, logical k16-step t, k-half kh) under the staging swizzle.
static __device__ __forceinline__ int frag_off32(int row, int t, int kh) {
  return row * 32 + 8 * ((2 * t + kh) ^ ((row >> 1) & 3));
}

// ---------------------------------------------------------------------------
// Plain bf16 MFMA GEMM (32x32x16): C = alpha * A * Bt^T. 128x128, BK=32.
// EPI: 0 = f32 store, 3 = bf16 store. z-batched via element strides.
// ---------------------------------------------------------------------------
template <int EPI>
__global__ __launch_bounds__(256) void gemm_bf16(
    const __bf16* __restrict__ A, int lda, long long sAz,
    const __bf16* __restrict__ Bt, int ldb, long long sBz,
    void* __restrict__ C0v, int ldc, long long sCz,
    int K, float alpha)
{
  __shared__ __bf16 As[128 * 32];
  __shared__ __bf16 Bs[128 * 32];
  const int tid = threadIdx.x;
  const int wave = tid >> 6, lane = tid & 63;
  int m0, n0;
  swizzle_mn<4, 128>(m0, n0);
  A  += (size_t)blockIdx.z * sAz;
  Bt += (size_t)blockIdx.z * sBz;

  const int srow = lane >> 2;
  const int skk = 8 * ((lane & 3) ^ ((lane >> 3) & 3));
  const __bf16* gA0 = A  + (size_t)(m0 + wave * 32      + srow) * lda + skk;
  const __bf16* gA1 = A  + (size_t)(m0 + wave * 32 + 16 + srow) * lda + skk;
  const __bf16* gB0 = Bt + (size_t)(n0 + wave * 32      + srow) * ldb + skk;
  const __bf16* gB1 = Bt + (size_t)(n0 + wave * 32 + 16 + srow) * ldb + skk;
  const int ldsoff = wave * 1024;

  const int l31 = lane & 31, kh = lane >> 5;
  const int wm = (wave & 1) * 64, wn = (wave >> 1) * 64;
  int aoff[2][2], boff[2][2];
#pragma unroll
  for (int i = 0; i < 2; i++)
#pragma unroll
    for (int t = 0; t < 2; t++) {
      aoff[i][t] = frag_off32(wm + i * 32 + l31, t, kh);
      boff[i][t] = frag_off32(wn + i * 32 + l31, t, kh);
    }

  floatx16 acc[2][2];
#pragma unroll
  for (int i = 0; i < 2; i++)
#pragma unroll
    for (int j = 0; j < 2; j++)
#pragma unroll
      for (int e = 0; e < 16; e++) acc[i][j][e] = 0.f;

  for (int k0 = 0; k0 < K; k0 += 32) {
    gll16(gA0, As + ldsoff); gll16(gA1, As + ldsoff + 512);
    gll16(gB0, Bs + ldsoff); gll16(gB1, Bs + ldsoff + 512);
    gA0 += 32; gA1 += 32; gB0 += 32; gB1 += 32;
    __syncthreads();
    bf16x8 af[2][2], bfv[2][2];
#pragma unroll
    for (int i = 0; i < 2; i++)
#pragma unroll
      for (int t = 0; t < 2; t++) {
        af[i][t]  = *(const bf16x8*)(As + aoff[i][t]);
        bfv[i][t] = *(const bf16x8*)(Bs + boff[i][t]);
      }
#pragma unroll
    for (int t = 0; t < 2; t++)
#pragma unroll
      for (int i = 0; i < 2; i++)
#pragma unroll
        for (int j = 0; j < 2; j++)
          acc[i][j] = __builtin_amdgcn_mfma_f32_32x32x16_bf16(
              af[i][t], bfv[j][t], acc[i][j], 0, 0, 0);
    __syncthreads();
  }

  // C/D: col = lane&31, row = (reg&3) + 8*(reg>>2) + 4*kh  [m74/m101]
  const int rb = m0 + wm + 4 * kh;
  const int cb = n0 + wn + l31;
#pragma unroll
  for (int i = 0; i < 2; i++) {
#pragma unroll
    for (int j = 0; j < 2; j++) {
      int c = cb + j * 32;
#pragma unroll
      for (int q = 0; q < 4; q++) {
        int r = rb + i * 32 + 8 * q;
        float v0 = acc[i][j][q * 4 + 0] * alpha;
        float v1 = acc[i][j][q * 4 + 1] * alpha;
        float v2 = acc[i][j][q * 4 + 2] * alpha;
        float v3 = acc[i][j][q * 4 + 3] * alpha;
        if (EPI == 0) {
          float* C = (float*)C0v + (size_t)blockIdx.z * sCz;
          float* p = C + (size_t)r * ldc + c;
          p[0] = v0; p[ldc] = v1; p[2 * ldc] = v2; p[3 * ldc] = v3;
        } else {  // EPI == 3: bf16 store
          __bf16* C = (__bf16*)C0v + (size_t)blockIdx.z * sCz;
          C[(size_t)r * ldc + c] = (__bf16)v0;
          C[(size_t)(r + 1) * ldc + c] = (__bf16)v1;
          C[(size_t)(r + 2) * ldc + c] = (__bf16)v2;
          C[(size_t)(r + 3) * ldc + c] = (__bf16)v3;
        }
      }
    }
  }
}

// ---------------------------------------------------------------------------
// Fused split-bf16 GEMM (16x16x32, conflict-free):
// C = alpha * (Ah*Bh^T + Al*Bh^T + Ah*Bl^T). 48 MFMA per 32-k step.
// EPI: 0 = f32 store, 2 = split hi/lo bf16 store. GROUP=8 swizzle.
// z-batched via element strides (used as split-K for qkm-km: sAz=sBz=512).
// ---------------------------------------------------------------------------
template <int EPI>
__global__ __launch_bounds__(256) void gemm_split(
    const __bf16* __restrict__ Ah, const __bf16* __restrict__ Al, int lda, long long sAz,
    const __bf16* __restrict__ Bh, const __bf16* __restrict__ Bl, int ldb, long long sBz,
    void* __restrict__ C0v, void* __restrict__ C1v, int ldc, long long sCz,
    int K, float alpha)
{
  __shared__ __bf16 Ash[128 * 32];
  __shared__ __bf16 Asl[128 * 32];
  __shared__ __bf16 Bsh[128 * 32];
  __shared__ __bf16 Bsl[128 * 32];
  const int tid = threadIdx.x;
  const int wave = tid >> 6, lane = tid & 63;
  int m0, n0;
  swizzle_mn<8, 128>(m0, n0);
  Ah += (size_t)blockIdx.z * sAz;
  Al += (size_t)blockIdx.z * sAz;
  Bh += (size_t)blockIdx.z * sBz;
  Bl += (size_t)blockIdx.z * sBz;

  const int srow = lane >> 2;
  const int skk = 8 * ((lane & 3) ^ ((lane >> 3) & 3));
  const size_t ao0 = (size_t)(m0 + wave * 32      + srow) * lda + skk;
  const size_t ao1 = (size_t)(m0 + wave * 32 + 16 + srow) * lda + skk;
  const size_t bo0 = (size_t)(n0 + wave * 32      + srow) * ldb + skk;
  const size_t bo1 = (size_t)(n0 + wave * 32 + 16 + srow) * ldb + skk;
  const __bf16 *gAh0 = Ah + ao0, *gAh1 = Ah + ao1;
  const __bf16 *gAl0 = Al + ao0, *gAl1 = Al + ao1;
  const __bf16 *gBh0 = Bh + bo0, *gBh1 = Bh + bo1;
  const __bf16 *gBl0 = Bl + bo0, *gBl1 = Bl + bo1;
  const int ldsoff = wave * 1024;

  const int fr = lane & 15, fq = lane >> 4;
  const int wm = (wave & 1) * 64, wn = (wave >> 1) * 64;
  int aoff[4], boff[4];
#pragma unroll
  for (int t = 0; t < 4; t++) {
    int rA = wm + t * 16 + fr;
    aoff[t] = rA * 32 + 8 * (fq ^ ((rA >> 1) & 3));
    int rB = wn + t * 16 + fr;
    boff[t] = rB * 32 + 8 * (fq ^ ((rB >> 1) & 3));
  }

  floatx4 acc[4][4];
#pragma unroll
  for (int i = 0; i < 4; i++)
#pragma unroll
    for (int j = 0; j < 4; j++) acc[i][j] = (floatx4){0.f, 0.f, 0.f, 0.f};

  for (int k0 = 0; k0 < K; k0 += 32) {
    gll16(gAh0, Ash + ldsoff); gll16(gAh1, Ash + ldsoff + 512);
    gll16(gAl0, Asl + ldsoff); gll16(gAl1, Asl + ldsoff + 512);
    gll16(gBh0, Bsh + ldsoff); gll16(gBh1, Bsh + ldsoff + 512);
    gll16(gBl0, Bsl + ldsoff); gll16(gBl1, Bsl + ldsoff + 512);
    gAh0 += 32; gAh1 += 32; gAl0 += 32; gAl1 += 32;
    gBh0 += 32; gBh1 += 32; gBl0 += 32; gBl1 += 32;
    __syncthreads();
    bf16x8 afh[4], afl[4], bfh[4], bfl[4];
#pragma unroll
    for (int t = 0; t < 4; t++) {
      afh[t] = *(const bf16x8*)(Ash + aoff[t]);
      afl[t] = *(const bf16x8*)(Asl + aoff[t]);
      bfh[t] = *(const bf16x8*)(Bsh + boff[t]);
      bfl[t] = *(const bf16x8*)(Bsl + boff[t]);
    }
#pragma unroll
    for (int i = 0; i < 4; i++)
#pragma unroll
      for (int j = 0; j < 4; j++) {
        acc[i][j] = __builtin_amdgcn_mfma_f32_16x16x32_bf16(
            afh[i], bfh[j], acc[i][j], 0, 0, 0);
        acc[i][j] = __builtin_amdgcn_mfma_f32_16x16x32_bf16(
            afl[i], bfh[j], acc[i][j], 0, 0, 0);
        acc[i][j] = __builtin_amdgcn_mfma_f32_16x16x32_bf16(
            afh[i], bfl[j], acc[i][j], 0, 0, 0);
      }
    __syncthreads();
  }

  const int rb = m0 + wm + fq * 4;
  const int cb = n0 + wn + fr;
#pragma unroll
  for (int i = 0; i < 4; i++) {
#pragma unroll
    for (int j = 0; j < 4; j++) {
      float vv[4] = {acc[i][j].x * alpha, acc[i][j].y * alpha,
                     acc[i][j].z * alpha, acc[i][j].w * alpha};
      int r = rb + i * 16, c = cb + j * 16;
      if (EPI == 0) {
        float* C = (float*)C0v + (size_t)blockIdx.z * sCz;
        float* p = C + (size_t)r * ldc + c;
        p[0] = vv[0]; p[ldc] = vv[1]; p[2 * ldc] = vv[2]; p[3 * ldc] = vv[3];
      } else {  // EPI == 2: split hi/lo
        __bf16* Hp = (__bf16*)C0v + (size_t)blockIdx.z * sCz;
        __bf16* Lp = (__bf16*)C1v + (size_t)blockIdx.z * sCz;
#pragma unroll
        for (int t = 0; t < 4; t++) {
          size_t o = (size_t)(r + t) * ldc + c;
          __bf16 hh = (__bf16)vv[t];
          Hp[o] = hh;
          Lp[o] = (__bf16)(vv[t] - (float)hh);
        }
      }
    }
  }
}

// ---------------------------------------------------------------------------
// 8-phase 256x256 split-bf16 GEMM (R21 version, 16x16x32). 8 waves, BK=32,
// 8 STATICALLY DISTINCT LDS buffers. NO mid-tile barriers — waves free-run
// within a K-tile; only the boundary __syncthreads (vmcnt drain) remains.
// Loads paced 3/3/2/0. Conflict-free (measured 0).
// EPI: 0 = f32 store (alpha), 2 = split hi/lo bf16 store.
// ---------------------------------------------------------------------------
#define MFMA1(a, b, c) c = __builtin_amdgcn_mfma_f32_16x16x32_bf16(a, b, c, 0, 0, 0)

#define MFMA_PAIR(i0, i1)                                                   \
  __builtin_amdgcn_s_setprio(1);                                            \
  _Pragma("unroll") for (int j = 0; j < 4; j++) {                           \
    MFMA1(a0h, bh[j], acc[i0][j]); MFMA1(a1h, bh[j], acc[i1][j]);           \
    MFMA1(a0l, bh[j], acc[i0][j]); MFMA1(a1l, bh[j], acc[i1][j]);           \
    MFMA1(a0h, bl[j], acc[i0][j]); MFMA1(a1h, bl[j], acc[i1][j]);           \
  }                                                                         \
  __builtin_amdgcn_s_setprio(0)

#define TILE8P(SAh, SAl, SBh, SBl, DAh, DAl, DBh, DBl, PF)                  \
  do {                                                                      \
    bf16x8 bh[4], bl[4];                                                    \
    _Pragma("unroll") for (int j = 0; j < 4; j++) {                         \
      bh[j] = *(const bf16x8*)(SBh + boff[j]);                              \
      bl[j] = *(const bf16x8*)(SBl + boff[j]);                              \
    }                                                                       \
    /* ---- phase 0: i=0,1 ; prefetch Ah pair + Al first (3) ---- */        \
    bf16x8 a0h = *(const bf16x8*)(SAh + aoff[0]);                           \
    bf16x8 a0l = *(const bf16x8*)(SAl + aoff[0]);                           \
    bf16x8 a1h = *(const bf16x8*)(SAh + aoff[1]);                           \
    bf16x8 a1l = *(const bf16x8*)(SAl + aoff[1]);                           \
    if (PF) { gll16(pAh0, DAh + lw); gll16(pAh1, DAh + lw + 512);           \
              gll16(pAl0, DAl + lw);                                        \
              pAh0 += 32; pAh1 += 32; pAl0 += 32; }                         \
    MFMA_PAIR(0, 1);                                                        \
    /* ---- phase 1: i=2,3 ; prefetch Al second + Bh pair (3) ---- */       \
    a0h = *(const bf16x8*)(SAh + aoff[2]);                                  \
    a0l = *(const bf16x8*)(SAl + aoff[2]);                                  \
    a1h = *(const bf16x8*)(SAh + aoff[3]);                                  \
    a1l = *(const bf16x8*)(SAl + aoff[3]);                                  \
    if (PF) { gll16(pAl1, DAl + lw + 512);                                  \
              gll16(pBh0, DBh + lw); gll16(pBh1, DBh + lw + 512);           \
              pAl1 += 32; pBh0 += 32; pBh1 += 32; }                         \
    MFMA_PAIR(2, 3);                                                        \
    /* ---- phase 2: i=4,5 ; prefetch Bl pair (2) ---- */                   \
    a0h = *(const bf16x8*)(SAh + aoff[4]);                                  \
    a0l = *(const bf16x8*)(SAl + aoff[4]);                                  \
    a1h = *(const bf16x8*)(SAh + aoff[5]);                                  \
    a1l = *(const bf16x8*)(SAl + aoff[5]);                                  \
    if (PF) { gll16(pBl0, DBl + lw); gll16(pBl1, DBl + lw + 512);           \
              pBl0 += 32; pBl1 += 32; }                                     \
    MFMA_PAIR(4, 5);                                                        \
    /* ---- phase 3: i=6,7 ; NO loads ; boundary drain ---- */              \
    a0h = *(const bf16x8*)(SAh + aoff[6]);                                  \
    a0l = *(const bf16x8*)(SAl + aoff[6]);                                  \
    a1h = *(const bf16x8*)(SAh + aoff[7]);                                  \
    a1l = *(const bf16x8*)(SAl + aoff[7]);                                  \
    MFMA_PAIR(6, 7);                                                        \
    __syncthreads();                                                        \
  } while (0)

template <int EPI>
__global__ __launch_bounds__(512) void gemm_split_8p(
    const __bf16* __restrict__ Ah, const __bf16* __restrict__ Al, int lda, long long sAz,
    const __bf16* __restrict__ Bh, const __bf16* __restrict__ Bl, int ldb, long long sBz,
    void* __restrict__ C0v, void* __restrict__ C1v, int ldc, long long sCz,
    int K, float alpha)
{
  // 8 statically distinct buffers: [4 matrices] x [double buffer], 16 KB each
  __shared__ __bf16 sAh0[256 * 32], sAl0[256 * 32], sBh0[256 * 32], sBl0[256 * 32];
  __shared__ __bf16 sAh1[256 * 32], sAl1[256 * 32], sBh1[256 * 32], sBl1[256 * 32];
  const int tid = threadIdx.x;
  const int wave = tid >> 6, lane = tid & 63;
  int m0, n0;
  swizzle_mn<4, 256>(m0, n0);
  Ah += (size_t)blockIdx.z * sAz;
  Al += (size_t)blockIdx.z * sAz;
  Bh += (size_t)blockIdx.z * sBz;
  Bl += (size_t)blockIdx.z * sBz;

  // staging: wave w loads rows [w*32, w*32+32) of each matrix k-slab,
  // pre-swizzled on the global side (same involution as the fragment reads)
  const int srow = lane >> 2;
  const int skk = 8 * ((lane & 3) ^ ((lane >> 3) & 3));
  const __bf16* pAh0 = Ah + (size_t)(m0 + wave * 32 + srow) * lda + skk;
  const __bf16* pAh1 = pAh0 + (size_t)16 * lda;
  const __bf16* pAl0 = Al + (size_t)(m0 + wave * 32 + srow) * lda + skk;
  const __bf16* pAl1 = pAl0 + (size_t)16 * lda;
  const __bf16* pBh0 = Bh + (size_t)(n0 + wave * 32 + srow) * ldb + skk;
  const __bf16* pBh1 = pBh0 + (size_t)16 * ldb;
  const __bf16* pBl0 = Bl + (size_t)(n0 + wave * 32 + srow) * ldb + skk;
  const __bf16* pBl1 = pBl0 + (size_t)16 * ldb;
  const int lw = wave * 1024;   // 32 rows * 32 elems per wave

  // fragment geometry: wave tile 128(m) x 64(n); 8 m-frags, 4 n-frags
  const int fr = lane & 15, fq = lane >> 4;
  const int wm = (wave >> 2) * 128, wn = (wave & 3) * 64;
  int aoff[8], boff[4];
#pragma unroll
  for (int i = 0; i < 8; i++) {
    int rA = wm + i * 16 + fr;
    aoff[i] = rA * 32 + 8 * (fq ^ ((rA >> 1) & 3));
  }
#pragma unroll
  for (int j = 0; j < 4; j++) {
    int rB = wn + j * 16 + fr;
    boff[j] = rB * 32 + 8 * (fq ^ ((rB >> 1) & 3));
  }

  floatx4 acc[8][4];
#pragma unroll
  for (int i = 0; i < 8; i++)
#pragma unroll
    for (int j = 0; j < 4; j++) acc[i][j] = (floatx4){0.f, 0.f, 0.f, 0.f};

  const int ktiles = K >> 5;          // must be even

  // prologue: stage tile 0 into set 0
  gll16(pAh0, sAh0 + lw); gll16(pAh1, sAh0 + lw + 512); pAh0 += 32; pAh1 += 32;
  gll16(pAl0, sAl0 + lw); gll16(pAl1, sAl0 + lw + 512); pAl0 += 32; pAl1 += 32;
  gll16(pBh0, sBh0 + lw); gll16(pBh1, sBh0 + lw + 512); pBh0 += 32; pBh1 += 32;
  gll16(pBl0, sBl0 + lw); gll16(pBl1, sBl0 + lw + 512); pBl0 += 32; pBl1 += 32;
  __syncthreads();

  for (int it = 0; it < (ktiles >> 1); ++it) {
    TILE8P(sAh0, sAl0, sBh0, sBl0, sAh1, sAl1, sBh1, sBl1,
           (2 * it + 1 < ktiles));
    TILE8P(sAh1, sAl1, sBh1, sBl1, sAh0, sAl0, sBh0, sBl0,
           (2 * it + 2 < ktiles));
  }

  // epilogue: C/D map col=lane&15, row=(lane>>4)*4+reg
  const int rb = m0 + wm + fq * 4;
  const int cb = n0 + wn + fr;
#pragma unroll
  for (int i = 0; i < 8; i++) {
#pragma unroll
    for (int j = 0; j < 4; j++) {
      int r = rb + i * 16, c = cb + j * 16;
      float vv[4] = {acc[i][j].x * alpha, acc[i][j].y * alpha,
                     acc[i][j].z * alpha, acc[i][j].w * alpha};
      if (EPI == 0) {
        float* C = (float*)C0v + (size_t)blockIdx.z * sCz;
        float* p = C + (size_t)r * ldc + c;
        p[0] = vv[0]; p[ldc] = vv[1]; p[2 * ldc] = vv[2]; p[3 * ldc] = vv[3];
      } else {  // EPI == 2: split hi/lo bf16
        __bf16* Hp = (__bf16*)C0v + (size_t)blockIdx.z * sCz;
        __bf16* Lp = (__bf16*)C1v + (size_t)blockIdx.z * sCz;
#pragma unroll
        for (int t = 0; t < 4; t++) {
          size_t o = (size_t)(r + t) * ldc + c;
          __bf16 hh = (__bf16)vv[t];
          Hp[o] = hh;
          Lp[o] = (__bf16)(vv[t] - (float)hh);
        }
      }
    }
  }
}

// ---------------------------------------------------------------------------
// 8-phase plain-bf16 GEMM (R20 version), tile 256(m) x 128(n), BK=64 as two
// 32-k slabs. 4 phases of 8 MFMA WITH mid-tile s_barriers (thin phases
// need the lockstep per R20/R21 A/B); loads 2/2/2/0; one __syncthreads per
// K-tile. 8 waves as 4Mx2N (64x64/wave), acc[4][4]; 96 KB LDS.
// EPI: 0 = f32 store, 3 = bf16 store.
// ---------------------------------------------------------------------------
#define PTILE(SA0, SA1, SB0, SB1, DA0, DA1, DB0, DB1, PF)                   \
  do {                                                                      \
    /* ---- phase 0: b0 frags + i=0,1 khalf0 ; 2 A loads ---- */            \
    bf16x8 b0[4], b1[4];                                                    \
    _Pragma("unroll") for (int j = 0; j < 4; j++)                           \
      b0[j] = *(const bf16x8*)(SB0 + boff[j]);                              \
    bf16x8 a00 = *(const bf16x8*)(SA0 + aoff[0]);                           \
    bf16x8 a10 = *(const bf16x8*)(SA0 + aoff[1]);                           \
    if (PF) { gll16(pA0, DA0 + lw); gll16(pA1, DA0 + lw + 512); }           \
    __builtin_amdgcn_s_setprio(1);                                          \
    _Pragma("unroll") for (int j = 0; j < 4; j++) {                         \
      MFMA1(a00, b0[j], acc[0][j]); MFMA1(a10, b0[j], acc[1][j]);           \
    }                                                                       \
    __builtin_amdgcn_s_setprio(0);                                          \
    __builtin_amdgcn_s_barrier();                                           \
    /* ---- phase 1: b1 frags + i=0,1 khalf1 ; 2 A loads ---- */            \
    _Pragma("unroll") for (int j = 0; j < 4; j++)                           \
      b1[j] = *(const bf16x8*)(SB1 + boff[j]);                              \
    bf16x8 a01 = *(const bf16x8*)(SA1 + aoff[0]);                           \
    bf16x8 a11 = *(const bf16x8*)(SA1 + aoff[1]);                           \
    if (PF) { gll16(pA0 + 32, DA1 + lw); gll16(pA1 + 32, DA1 + lw + 512);   \
              pA0 += 64; pA1 += 64; }                                       \
    __builtin_amdgcn_s_setprio(1);                                          \
    _Pragma("unroll") for (int j = 0; j < 4; j++) {                         \
      MFMA1(a01, b1[j], acc[0][j]); MFMA1(a11, b1[j], acc[1][j]);           \
    }                                                                       \
    __builtin_amdgcn_s_setprio(0);                                          \
    __builtin_amdgcn_s_barrier();                                           \
    /* ---- phase 2: i=2,3 khalf0 ; 2 B loads ---- */                       \
    bf16x8 a20 = *(const bf16x8*)(SA0 + aoff[2]);                           \
    bf16x8 a30 = *(const bf16x8*)(SA0 + aoff[3]);                           \
    if (PF) { gll16(pB0, DB0 + lwB); gll16(pB0 + 32, DB1 + lwB);            \
              pB0 += 64; }                                                  \
    __builtin_amdgcn_s_setprio(1);                                          \
    _Pragma("unroll") for (int j = 0; j < 4; j++) {                         \
      MFMA1(a20, b0[j], acc[2][j]); MFMA1(a30, b0[j], acc[3][j]);           \
    }                                                                       \
    __builtin_amdgcn_s_setprio(0);                                          \
    __builtin_amdgcn_s_barrier();                                           \
    /* ---- phase 3: i=2,3 khalf1 ; NO loads ; boundary drain ---- */       \
    bf16x8 a21 = *(const bf16x8*)(SA1 + aoff[2]);                           \
    bf16x8 a31 = *(const bf16x8*)(SA1 + aoff[3]);                           \
    __builtin_amdgcn_s_setprio(1);                                          \
    _Pragma("unroll") for (int j = 0; j < 4; j++) {                         \
      MFMA1(a21, b1[j], acc[2][j]); MFMA1(a31, b1[j], acc[3][j]);           \
    }                                                                       \
    __builtin_amdgcn_s_setprio(0);                                          \
    __syncthreads();                                                        \
  } while (0)

template <int EPI>
__global__ __launch_bounds__(512) void gemm_bf16_8p(
    const __bf16* __restrict__ A, int lda, long long sAz,
    const __bf16* __restrict__ Bt, int ldb, long long sBz,
    void* __restrict__ C0v, int ldc, long long sCz,
    int K, float alpha)
{
  // A slabs 256x32 (16 KB), B slabs 128x32 (8 KB); x2 k-halves x2 dbuf = 96 KB
  __shared__ __bf16 sA0_0[256 * 32], sA1_0[256 * 32];
  __shared__ __bf16 sB0_0[128 * 32], sB1_0[128 * 32];
  __shared__ __bf16 sA0_1[256 * 32], sA1_1[256 * 32];
  __shared__ __bf16 sB0_1[128 * 32], sB1_1[128 * 32];
  const int tid = threadIdx.x;
  const int wave = tid >> 6, lane = tid & 63;
  int m0, n0;
  swizzle_mn2<4, 256, 128>(m0, n0);
  A  += (size_t)blockIdx.z * sAz;
  Bt += (size_t)blockIdx.z * sBz;

  // staging (global-side XOR pre-swizzle, same involution as frag reads):
  // A: wave stages rows [w*32, w*32+32); B: rows [w*16, w*16+16).
  const int srow = lane >> 2;
  const int skk = 8 * ((lane & 3) ^ ((lane >> 3) & 3));
  const __bf16* pA0 = A + (size_t)(m0 + wave * 32 + srow) * lda + skk;
  const __bf16* pA1 = pA0 + (size_t)16 * lda;
  const __bf16* pB0 = Bt + (size_t)(n0 + wave * 16 + srow) * ldb + skk;
  const int lw = wave * 1024;   // A: 32 rows * 32 elems
  const int lwB = wave * 512;   // B: 16 rows * 32 elems

  // fragment geometry: wave tile 64(m) x 64(n); 4 m-frags, 4 n-frags
  const int fr = lane & 15, fq = lane >> 4;
  const int wm = (wave >> 1) * 64, wn = (wave & 1) * 64;
  int aoff[4], boff[4];
#pragma unroll
  for (int i = 0; i < 4; i++) {
    int rA = wm + i * 16 + fr;
    aoff[i] = rA * 32 + 8 * (fq ^ ((rA >> 1) & 3));
    int rB = wn + i * 16 + fr;
    boff[i] = rB * 32 + 8 * (fq ^ ((rB >> 1) & 3));
  }

  floatx4 acc[4][4];
#pragma unroll
  for (int i = 0; i < 4; i++)
#pragma unroll
    for (int j = 0; j < 4; j++) acc[i][j] = (floatx4){0.f, 0.f, 0.f, 0.f};

  const int ktiles = K >> 6;          // BK=64; must be even

  // prologue: stage tile 0 into set 0
  gll16(pA0, sA0_0 + lw); gll16(pA1, sA0_0 + lw + 512);
  gll16(pA0 + 32, sA1_0 + lw); gll16(pA1 + 32, sA1_0 + lw + 512);
  gll16(pB0, sB0_0 + lwB); gll16(pB0 + 32, sB1_0 + lwB);
  pA0 += 64; pA1 += 64; pB0 += 64;
  __syncthreads();

  for (int it = 0; it < (ktiles >> 1); ++it) {
    PTILE(sA0_0, sA1_0, sB0_0, sB1_0, sA0_1, sA1_1, sB0_1, sB1_1,
          (2 * it + 1 < ktiles));
    PTILE(sA0_1, sA1_1, sB0_1, sB1_1, sA0_0, sA1_0, sB0_0, sB1_0,
          (2 * it + 2 < ktiles));
  }

  // epilogue: C/D map col=lane&15, row=(lane>>4)*4+reg
  const int rb = m0 + wm + fq * 4;
  const int cb = n0 + wn + fr;
#pragma unroll
  for (int i = 0; i < 4; i++) {
#pragma unroll
    for (int j = 0; j < 4; j++) {
      int r = rb + i * 16, c = cb + j * 16;
      float vv[4] = {acc[i][j].x * alpha, acc[i][j].y * alpha,
                     acc[i][j].z * alpha, acc[i][j].w * alpha};
      if (EPI == 0) {
        float* C = (float*)C0v + (size_t)blockIdx.z * sCz;
        float* p = C + (size_t)r * ldc + c;
        p[0] = vv[0]; p[ldc] = vv[1]; p[2 * ldc] = vv[2]; p[3 * ldc] = vv[3];
      } else {  // EPI == 3: bf16 store
        __bf16* C = (__bf16*)C0v + (size_t)blockIdx.z * sCz;
        C[(size_t)r * ldc + c] = (__bf16)vv[0];
        C[(size_t)(r + 1) * ldc + c] = (__bf16)vv[1];
        C[(size_t)(r + 2) * ldc + c] = (__bf16)vv[2];
        C[(size_t)(r + 3) * ldc + c] = (__bf16)vv[3];
      }
    }
  }
}

// ---------------------------------------------------------------------------
// Wave-per-row in-place softmax: f32 row [2048] -> bf16 into same row.
// ---------------------------------------------------------------------------
__global__ __launch_bounds__(256) void softmax_wave(float* __restrict__ Pf)
{
  const int wave = threadIdx.x >> 6, lane = threadIdx.x & 63;
  const size_t row = (size_t)blockIdx.x * 4 + wave;
  float* p = Pf + row * 2048;
  __bf16* q = (__bf16*)p;

  float4 v[8];
  float m = -1e30f;
#pragma unroll
  for (int t = 0; t < 8; t++) {
    v[t] = ((const float4*)p)[lane + t * 64];
    m = fmaxf(m, fmaxf(fmaxf(v[t].x, v[t].y), fmaxf(v[t].z, v[t].w)));
  }
#pragma unroll
  for (int off = 32; off; off >>= 1) m = fmaxf(m, __shfl_xor(m, off, 64));

  float s = 0.f;
#pragma unroll
  for (int t = 0; t < 8; t++) {
    v[t].x = expf(v[t].x - m); v[t].y = expf(v[t].y - m);
    v[t].z = expf(v[t].z - m); v[t].w = expf(v[t].w - m);
    s += (v[t].x + v[t].y) + (v[t].z + v[t].w);
  }
#pragma unroll
  for (int off = 32; off; off >>= 1) s += __shfl_xor(s, off, 64);
  float inv = 1.0f / s;

#pragma unroll
  for (int t = 0; t < 8; t++) {
    bf16x4 o;
    o.x = (__bf16)(v[t].x * inv); o.y = (__bf16)(v[t].y * inv);
    o.z = (__bf16)(v[t].z * inv); o.w = (__bf16)(v[t].w * inv);
    *(bf16x4*)(q + (lane + t * 64) * 4) = o;
  }
}

// ---------------------------------------------------------------------------
extern "C" void kernel_launch(void* const* d_in, const int* in_sizes, int n_in,
                              void* d_out, int out_size, void* d_ws, size_t ws_size,
                              hipStream_t stream)
{
  (void)in_sizes; (void)n_in; (void)out_size; (void)ws_size;
  const float* x     = (const float*)d_in[0];
  const float* blade = (const float*)d_in[1];
  const float* w_q   = (const float*)d_in[2];
  const float* w_k   = (const float*)d_in[3];
  const float* w_v   = (const float*)d_in[4];
  const float* w_o   = (const float*)d_in[5];
  float* out = (float*)d_out;

  // --- fixed aliased workspace plan (peak 234,881,024 B; ws >= 256 MB) -----
  char* base = (char*)d_ws;
  __bf16* wbo   = (__bf16*)(base);                  //  16.78 MB [1024,8192]
  __bf16* vT    = (__bf16*)(base + 16777216);       //   8.39 MB [1024,4096]
  __bf16* qkmh  = (__bf16*)(base + 25165824);       //  37.75 MB [4096,4608]
  __bf16* qkml  = (__bf16*)(base + 62914560);       //  37.75 MB
  char* scr = base + 100663296;
  // phase 1 (aliases Pf region):
  __bf16* xh    = (__bf16*)(scr);                   //   8.39 MB [4096,1024]
  __bf16* xl    = (__bf16*)(scr + 8388608);         //   8.39 MB
  __bf16* wbqkh = (__bf16*)(scr + 16777216);        //   9.44 MB [4608,1024]
  __bf16* wbqkl = (__bf16*)(scr + 26214400);        //   9.44 MB
  __bf16* wbv   = (__bf16*)(scr + 35651584);        //   2.10 MB [1024,1024]
  float*  kmP   = (float*)(scr + 37748736);         //  16.78 MB [2,4096,512]
  // phase 2/3:
  float*  Pf    = (float*)(scr);                    //  67.11 MB [4,2048,2048]
  __bf16* A2    = (__bf16*)(scr + 67108864);        //  33.55 MB [2048,8192]
  float*  Part  = (float*)(scr + 100663296);        //  33.55 MB [4,2048,1024]

  dim3 blk(256);
  const float scale = 0.04419417382415922f;  // 1/sqrt(512)

  // --- phase 1: prep + projections ----------------------------------------
  prep2<<<10752, blk, 0, stream>>>(x, blade, w_q, w_k, w_v, w_o,
                                   xh, xl, wbqkh, wbqkl, wbv, wbo);

  // qkm q-part: [4096,1024] x [4096,1024]^T -> cols 0..4095 of qkm.
  // 256^2 8-phase: grid 16x16 = 256 blocks = exactly 1 per CU.
  gemm_split_8p<2><<<dim3(16, 16, 1), dim3(512), 0, stream>>>(
      xh, xl, 1024, 0, wbqkh, wbqkl, 1024, 0,
      qkmh, qkml, 4608, 0, 1024, 1.f);

  // qkm km-part: [4096,1024] x [512,1024]^T, split-K=2 via z (full fill:
  // grid 4x32x2 = 256 blocks). f32 partials -> kmP, then split2km merges.
  gemm_split<0><<<dim3(4, 32, 2), blk, 0, stream>>>(
      xh, xl, 1024, 512,
      wbqkh + (size_t)4096 * 1024, wbqkl + (size_t)4096 * 1024, 1024, 512,
      kmP, nullptr, 512, (long long)4096 * 512, 512, 1.f);
  split2km<<<2048, blk, 0, stream>>>(kmP, qkmh + 4096, qkml + 4096);

  // vT = wbv * xh^T : [1024,1024] x [4096,1024]^T -> [1024,4096] bf16
  gemm_bf16<3><<<dim3(32, 8, 1), blk, 0, stream>>>(
      wbv, 1024, 0, xh, 1024, 0, vT, 4096, 0, 1024, 1.f);

  // --- phase 2/3: attention + O-projection per batch -----------------------
  for (int b = 0; b < 2; b++) {
    const __bf16* qh_b  = qkmh + (size_t)b * 2048 * 4608;
    const __bf16* ql_b  = qkml + (size_t)b * 2048 * 4608;
    const __bf16* kmh_b = qh_b + 4096;   // km cols 4096..4607, ldb 4608
    const __bf16* kml_b = ql_b + 4096;

    for (int h0 = 0; h0 < 8; h0 += 4) {
      // scores -> Pf [z,2048,2048] f32 (z = head in group)
      // 8-phase 256^2 tiles: grid 8x8x4 = 256 blocks = exactly 1 per CU
      gemm_split_8p<0><<<dim3(8, 8, 4), dim3(512), 0, stream>>>(
          qh_b + h0 * 512, ql_b + h0 * 512, 4608, 512,
          kmh_b, kml_b, 4608, 0,
          Pf, nullptr, 2048, (long long)2048 * 2048, 512, scale);
      // softmax in place: bf16 P into Pf rows (row stride 4096 bf16 units)
      softmax_wave<<<4 * 2048 / 4, blk, 0, stream>>>(Pf);
      // PV: P [z,2048,2048] * vT_b^T -> A2 cols (h0+z)*1024
      // 8-phase 256x128 tiles: grid 8x8x4 = 256 blocks = 1 per CU
      gemm_bf16_8p<3><<<dim3(8, 8, 4), dim3(512), 0, stream>>>(
          (const __bf16*)Pf, 4096, (long long)2048 * 4096,
          vT + (size_t)b * 2048, 4096, 0,
          A2 + (size_t)h0 * 1024, 8192, 1024, 2048, 1.f);
    }

    // O-proj: A2 [2048,8192] x wbo [1024,8192]^T, split-K=4 -> partials
    // 8-phase 256x128 tiles: grid 8x8x4 = 256 blocks = 1 per CU
    gemm_bf16_8p<0><<<dim3(8, 8, 4), dim3(512), 0, stream>>>(
        A2, 8192, 2048, wbo, 8192, 2048,
        Part, 1024, (long long)2048 * 1024, 2048, 1.f);
    reduce4<<<2048, blk, 0, stream>>>(Part, out + (size_t)b * 2048 * 1024,
                                      2048 * 1024);
  }
}